// Round 13
// baseline (120.232 us; speedup 1.0000x reference)
//
#include <hip/hip_runtime.h>
#include <hip/hip_bf16.h>
#include <stdint.h>

typedef __attribute__((ext_vector_type(8))) short short8;
typedef __attribute__((ext_vector_type(4))) float f32x4;
using bf16 = __hip_bfloat16;

#define MFMA16(a, b, c) __builtin_amdgcn_mfma_f32_16x16x32_bf16((a), (b), (c), 0, 0, 0)

#define GLOAD_LDS16(g, l) __builtin_amdgcn_global_load_lds( \
    (const __attribute__((address_space(1))) void*)(g),     \
    (__attribute__((address_space(3))) void*)(l), 16, 0, 0)

__device__ __forceinline__ unsigned packbf2(float lo, float hi) {
  unsigned r;
  asm("v_cvt_pk_bf16_f32 %0, %1, %2" : "=v"(r) : "v"(lo), "v"(hi));
  return r;
}
__device__ __forceinline__ float ex2(float x) {
  float r;
  asm("v_exp_f32 %0, %1" : "=v"(r) : "v"(x));
  return r;
}
__device__ __forceinline__ f32x4 vmax4(f32x4 a, f32x4 b) {
  f32x4 r;
  r[0] = fmaxf(a[0], b[0]); r[1] = fmaxf(a[1], b[1]);
  r[2] = fmaxf(a[2], b[2]); r[3] = fmaxf(a[3], b[3]);
  return r;
}

template <bool EDGE>
__device__ __forceinline__ void p1_update(const f32x4* sv, float& m, float& l,
                                          int kb0, int myq, int lhi) {
  f32x4 t4 = vmax4(vmax4(sv[0], sv[1]), vmax4(sv[2], sv[3]));
  float tm = fmaxf(fmaxf(t4[0], t4[1]), fmaxf(t4[2], t4[3]));
  float nm = fmaxf(m, tm);
  float sc = ex2(m - nm);
  float sum = 0.f;
#pragma unroll
  for (int nt = 0; nt < 4; ++nt) {
    float part = 0.f;
#pragma unroll
    for (int r = 0; r < 4; ++r) {
      float e = ex2(sv[nt][r] - nm);
      if (EDGE) {
        int key = kb0 + nt * 16 + lhi * 4 + r;
        bool ok = (key <= myq) && (key > myq - 512);
        e = ok ? e : 0.f;
      }
      part += e;
    }
    sum += part;
  }
  l = l * sc + sum;
  m = nm;
}

template <bool EDGE>
__device__ __forceinline__ float p2_probs(const f32x4* s1v, const f32x4* s2v,
                                          float m1, float m2, float c2,
                                          int kb0, int myq, int lhi, int l15,
                                          unsigned* pw) {
  float d0 = 0.f, d1 = 0.f;
#pragma unroll
  for (int nt = 0; nt < 4; ++nt) {
    float pr[4];
#pragma unroll
    for (int r = 0; r < 4; ++r) {
      float e1 = ex2(s1v[nt][r] - m1);
      float e2 = ex2(s2v[nt][r] - m2);
      float p = fmaf(-c2, e2, e1);
      p = fmaxf(p, 0.f);
      if (EDGE) {
        int key = kb0 + nt * 16 + lhi * 4 + r;
        bool ok = (key <= myq) && (key > myq - 512);
        p = ok ? p : 0.f;
      }
      pr[r] = p;
      if (r & 1) d1 += p; else d0 += p;
    }
    int pi = l15 * 36 + 8 * nt + 2 * lhi;
    pw[pi]     = packbf2(pr[0], pr[1]);
    pw[pi + 1] = packbf2(pr[2], pr[3]);
  }
  return d0 + d1;
}

// ================= fused prep: x f32 -> FT bf16, weights -> FT bf16 =================
// FT layout for an MxK operand (K=2048, nkc=64):
//   frag = (m>>4)*64 + (k>>5);  lane = (m&15) + 16*((k>>3)&3);  elem = k&7
//   offset = frag*512 + lane*8 + elem   (one 16x32 MFMA fragment = contiguous 1KB)
__global__ __launch_bounds__(256) void prep_all(const float* __restrict__ x,
                                                const float* __restrict__ Wq,
                                                const float* __restrict__ Wk,
                                                const float* __restrict__ Wv,
                                                const float* __restrict__ Wo,
                                                bf16* __restrict__ xbFT,
                                                bf16* __restrict__ WqkvFT,
                                                bf16* __restrict__ WoFT)
{
  const int bx = blockIdx.x;
  const int tid = threadIdx.x;
  if (bx >= 80) {
    int row = (bx - 80) * 32 + blockIdx.y;
    const float* f = x + (size_t)row * 2048 + tid * 8;
    float4 a = *(const float4*)f;
    float4 b = *(const float4*)(f + 4);
    union { bf16 h[8]; short8 s; } u;
    u.h[0] = __float2bfloat16(a.x); u.h[1] = __float2bfloat16(a.y);
    u.h[2] = __float2bfloat16(a.z); u.h[3] = __float2bfloat16(a.w);
    u.h[4] = __float2bfloat16(b.x); u.h[5] = __float2bfloat16(b.y);
    u.h[6] = __float2bfloat16(b.z); u.h[7] = __float2bfloat16(b.w);
    int frag = (row >> 4) * 64 + (tid >> 2);
    int ln   = (row & 15) + 16 * (tid & 3);
    *(short8*)(xbFT + (size_t)frag * 512 + ln * 8) = u.s;
    return;
  }
  const float* W;
  bf16* Wt;
  int N, n0;
  if (bx < 32)      { W = Wq; Wt = WqkvFT; N = 2048; n0 = bx * 64; }
  else if (bx < 40) { W = Wk; Wt = WqkvFT; N = 512;  n0 = 2048 + (bx - 32) * 64; }
  else if (bx < 48) { W = Wv; Wt = WqkvFT; N = 512;  n0 = 2560 + (bx - 40) * 64; }
  else              { W = Wo; Wt = WoFT;   N = 2048; n0 = (bx - 48) * 64; }
  const int nloc0 = (N == 512) ? (n0 - ((n0 >= 2560) ? 2560 : 2048)) : ((bx < 32 || bx >= 48) ? (n0 & 2047) : 0);
  const int k0 = blockIdx.y * 64;

  __shared__ bf16 t[64][72];
#pragma unroll
  for (int pass = 0; pass < 4; ++pass) {
    int r = pass * 16 + (tid >> 4);
    int c = (tid & 15) * 4;
    float4 v = *(const float4*)(W + (size_t)(k0 + r) * N + nloc0 + c);
    t[c + 0][r] = __float2bfloat16(v.x);
    t[c + 1][r] = __float2bfloat16(v.y);
    t[c + 2][r] = __float2bfloat16(v.z);
    t[c + 3][r] = __float2bfloat16(v.w);
  }
  __syncthreads();
#pragma unroll
  for (int pass = 0; pass < 2; ++pass) {
    int n = pass * 32 + (tid >> 3);
    int k8 = (tid & 7) * 8;
    int frag = ((n0 + n) >> 4) * 64 + ((k0 + k8) >> 5);
    int ln = (n & 15) + 16 * ((k8 >> 3) & 3);
    *(short8*)(Wt + (size_t)frag * 512 + ln * 8) = *(const short8*)(&t[n][k8]);
  }
}

// ================= bf16 V region [key][512] -> VT [512][2048] =================
__global__ __launch_bounds__(256) void transpose_v(const bf16* __restrict__ QKV,
                                                   bf16* __restrict__ VT)
{
  __shared__ bf16 t[64][72];
  const int tid = threadIdx.x;
  const int k0 = blockIdx.x * 64;
  const int d0 = blockIdx.y * 64;
#pragma unroll
  for (int pass = 0; pass < 2; ++pass) {
    int c = pass * 256 + tid;
    int r = c >> 3, cq = (c & 7) * 8;
    short8 v = *(const short8*)(QKV + (size_t)(k0 + r) * 3072 + 2560 + d0 + cq);
#pragma unroll
    for (int j = 0; j < 8; ++j) t[cq + j][r] = ((const bf16*)&v)[j];
  }
  __syncthreads();
#pragma unroll
  for (int pass = 0; pass < 2; ++pass) {
    int c = pass * 256 + tid;
    int d = c >> 3, kq = (c & 7) * 8;
    *(short8*)(VT + (size_t)(d0 + d) * 2048 + k0 + kq) = *(const short8*)(&t[d][kq]);
  }
}

// ================= GEMM: C = Aft @ Bft^T — both operands FT, direct-to-VGPR =================
// Zero LDS, zero barriers. 4-deep register ring, 8 loads/stage, counted vmcnt.
template <int CF32>
__global__ __launch_bounds__(256) void gemm_dd(const bf16* __restrict__ Aft,
                                               const bf16* __restrict__ Bft,
                                               void* __restrict__ C,
                                               int M, int N, int K)
{
  const int tid  = threadIdx.x;
  const int lane = tid & 63;
  const int w    = tid >> 6;
  const int wmg  = (w >> 1) * 4;
  const int wng  = (w & 1) * 4;
  const int l15  = lane & 15;
  const int lhi  = lane >> 4;
  const int bm0  = blockIdx.y * 128;
  const int bn0  = blockIdx.x * 128;
  const int nkc  = K >> 5;   // 64

  const bf16* abase[4];
  const bf16* bbase[4];
#pragma unroll
  for (int i = 0; i < 4; ++i) {
    abase[i] = Aft + ((size_t)((bm0 >> 4) + wmg + i) * nkc) * 512 + lane * 8;
    bbase[i] = Bft + ((size_t)((bn0 >> 4) + wng + i) * nkc) * 512 + lane * 8;
  }

  f32x4 acc[4][4];
  const f32x4 zero4 = {0.f, 0.f, 0.f, 0.f};
#pragma unroll
  for (int i = 0; i < 4; ++i)
#pragma unroll
    for (int j = 0; j < 4; ++j) acc[i][j] = zero4;

  short8 ar0[4], ar1[4], ar2[4], ar3[4];
  short8 br0[4], br1[4], br2[4], br3[4];

#define LOADS(ar, br, kc)                                                           \
  { _Pragma("unroll")                                                               \
    for (int i = 0; i < 4; ++i)                                                     \
      asm volatile("global_load_dwordx4 %0, %1, off"                                \
                   : "=v"(ar[i]) : "v"(abase[i] + (size_t)(kc) * 512) : "memory");  \
    _Pragma("unroll")                                                               \
    for (int i = 0; i < 4; ++i)                                                     \
      asm volatile("global_load_dwordx4 %0, %1, off"                                \
                   : "=v"(br[i]) : "v"(bbase[i] + (size_t)(kc) * 512) : "memory");  \
  }

#define KSTEP(ar, br, wcn, ...)                                                     \
  { asm volatile("s_waitcnt vmcnt(" #wcn ")" ::: "memory");                         \
    __builtin_amdgcn_sched_barrier(0);                                              \
    __VA_ARGS__                                                                     \
    _Pragma("unroll")                                                               \
    for (int mt = 0; mt < 4; ++mt)                                                  \
      _Pragma("unroll")                                                             \
      for (int nt = 0; nt < 4; ++nt)                                                \
        acc[mt][nt] = MFMA16(ar[mt], br[nt], acc[mt][nt]);                          \
  }

  LOADS(ar0, br0, 0);
  LOADS(ar1, br1, 1);
  LOADS(ar2, br2, 2);

  for (int t = 0; t + 8 <= nkc; t += 4) {
    KSTEP(ar0, br0, 16, LOADS(ar3, br3, t + 3);)
    KSTEP(ar1, br1, 16, LOADS(ar0, br0, t + 4);)
    KSTEP(ar2, br2, 16, LOADS(ar1, br1, t + 5);)
    KSTEP(ar3, br3, 16, LOADS(ar2, br2, t + 6);)
  }
  KSTEP(ar0, br0, 16, LOADS(ar3, br3, nkc - 1);)
  KSTEP(ar1, br1, 16, )
  KSTEP(ar2, br2, 8, )
  KSTEP(ar3, br3, 0, )
#undef LOADS
#undef KSTEP

#pragma unroll
  for (int mt = 0; mt < 4; ++mt) {
    int row0 = bm0 + (wmg + mt) * 16 + lhi * 4;
#pragma unroll
    for (int nt = 0; nt < 4; ++nt) {
      int col = bn0 + (wng + nt) * 16 + l15;
#pragma unroll
      for (int r = 0; r < 4; ++r) {
        float val = acc[mt][nt][r];
        size_t idx = (size_t)(row0 + r) * N + col;
        if (CF32) ((float*)C)[idx] = val;
        else ((bf16*)C)[idx] = __float2bfloat16(val);
      }
    }
  }
}

// ================= RoPE (in-place; Q scaled by 0.125*log2(e)) =================
__global__ __launch_bounds__(256) void rope2(bf16* __restrict__ QKV)
{
  const int NQ = 2048 * 16 * 8;
  int i = blockIdx.x * blockDim.x + threadIdx.x;
  bf16* base;
  int s, d0;
  float scale;
  if (i < NQ) {
    s = i >> 7;
    int rem = i & 127;
    int h = rem >> 3;
    d0 = (rem & 7) * 8;
    base = QKV + (size_t)s * 3072 + h * 128 + d0;
    scale = 0.180336880111120f;   // 0.125 * log2(e)
  } else {
    int j = i - NQ;
    if (j >= 2048 * 4 * 8) return;
    s = j >> 5;
    int rem = j & 31;
    int h = rem >> 3;
    d0 = (rem & 7) * 8;
    base = QKV + (size_t)s * 3072 + 2048 + h * 128 + d0;
    scale = 1.f;
  }
  short8 x1v = *(const short8*)base;
  short8 x2v = *(const short8*)(base + 64);
  union { bf16 h[8]; short8 v; } o1, o2;
#pragma unroll
  for (int e = 0; e < 8; ++e) {
    float inv = __expf(-(float)(d0 + e) * (9.210340371976184f / 64.0f));
    float ang = (float)s * inv;
    float c = __cosf(ang), sn = __sinf(ang);
    union { short s; bf16 b; } u1, u2;
    u1.s = x1v[e]; u2.s = x2v[e];
    float x1 = __bfloat162float(u1.b);
    float x2 = __bfloat162float(u2.b);
    o1.h[e] = __float2bfloat16((x1 * c - x2 * sn) * scale);
    o2.h[e] = __float2bfloat16((x2 * c + x1 * sn) * scale);
  }
  *(short8*)base = o1.v;
  *(short8*)(base + 64) = o2.v;
}

// ================= Differential sliding-window attention (swapped-QK, log2 domain) =================
// Output written in FT layout (A-operand of the Wo GEMM) via LDS restage.
__global__ __launch_bounds__(256) void diff_attn(const bf16* __restrict__ QKV,
                                                 const bf16* __restrict__ VT,
                                                 const float* __restrict__ lam,
                                                 bf16* __restrict__ ATTft)
{
  __shared__ __align__(16) bf16 Kb[2][64 * 128];
  __shared__ __align__(16) bf16 Vb[2][128 * 64];
  __shared__ __align__(16) bf16 Pw[4][16 * 72];

  const int qb   = blockIdx.x;
  const int h    = blockIdx.y;
  const int kvh  = h >> 2;
  const int tid  = threadIdx.x;
  const int lane = tid & 63;
  const int w    = tid >> 6;
  const int l15  = lane & 15;
  const int lhi  = lane >> 4;
  const int qg   = qb * 64 + w * 16;
  const int myq  = qg + l15;
  const float lamv = lam[h];

  const bf16* Kg = QKV + 2048 + (size_t)kvh * 128;
  const bf16* Vg = VT + (size_t)kvh * 128 * 2048;

  short8 qf[4];
  {
    const bf16* qrow = QKV + (size_t)myq * 3072 + h * 128;
#pragma unroll
    for (int c = 0; c < 4; ++c)
      qf[c] = *(const short8*)(qrow + c * 32 + lhi * 8);
  }

  const int t0 = (qb >= 8) ? (qb - 8) : 0;

#define STAGE_K(buf, kbase)                                                     \
  {                                                                             \
    _Pragma("unroll")                                                           \
    for (int p = 0; p < 4; ++p) {                                               \
      int c = p * 256 + tid;                                                    \
      int r = c >> 4, q = c & 15;                                               \
      GLOAD_LDS16(Kg + (size_t)((kbase) + r) * 3072 + ((q ^ (r & 7)) * 8),      \
                  &Kb[buf][c * 8]);                                             \
    }                                                                           \
  }
#define STAGE_V(buf, kbase)                                                     \
  {                                                                             \
    _Pragma("unroll")                                                           \
    for (int p = 0; p < 4; ++p) {                                               \
      int c = p * 256 + tid;                                                    \
      int d = c >> 3, q = c & 7;                                                \
      GLOAD_LDS16(Vg + (size_t)d * 2048 + (kbase) + ((q ^ (d & 7)) * 8),        \
                  &Vb[buf][c * 8]);                                             \
    }                                                                           \
  }
#define KFRAG(buf, nt, qc) \
  (*(const short8*)(&Kb[buf][(((nt) * 16 + l15) * 16 + ((qc) ^ (((nt) * 16 + l15) & 7))) * 8]))
#define VFRAG(buf, n, qc) \
  (*(const short8*)(&Vb[buf][(((n) * 16 + l15) * 8 + ((qc) ^ (((n) * 16 + l15) & 7))) * 8]))
#define QK_TILE(cur)                                            \
  _Pragma("unroll")                                             \
  for (int nt = 0; nt < 4; ++nt) {                              \
    f32x4 s1 = zero4, s2 = zero4;                               \
    s1 = MFMA16(KFRAG(cur, nt, lhi),      qf[0], s1);           \
    s1 = MFMA16(KFRAG(cur, nt, 4 + lhi),  qf[1], s1);           \
    s2 = MFMA16(KFRAG(cur, nt, 8 + lhi),  qf[2], s2);           \
    s2 = MFMA16(KFRAG(cur, nt, 12 + lhi), qf[3], s2);           \
    s1v[nt] = s1; s2v[nt] = s2;                                 \
  }

  const f32x4 zero4 = {0.f, 0.f, 0.f, 0.f};

  float m1 = -1e30f, l1 = 0.f, m2 = -1e30f, l2 = 0.f;
  STAGE_K(0, t0 * 64);
  __syncthreads();
  {
    int cur = 0;
    for (int t = t0; t <= qb; ++t, cur ^= 1) {
      if (t < qb) STAGE_K(cur ^ 1, (t + 1) * 64);
      const int kb0 = t * 64;
      f32x4 s1v[4], s2v[4];
      QK_TILE(cur);
      const bool edge = (t == qb) || (qb >= 8 && t == t0);
      if (edge) {
        p1_update<true>(s1v, m1, l1, kb0, myq, lhi);
        p1_update<true>(s2v, m2, l2, kb0, myq, lhi);
      } else {
        p1_update<false>(s1v, m1, l1, kb0, myq, lhi);
        p1_update<false>(s2v, m2, l2, kb0, myq, lhi);
      }
      __syncthreads();
    }
  }

#pragma unroll
  for (int mk = 16; mk <= 32; mk <<= 1) {
    float pm = __shfl_xor(m1, mk, 64), pl = __shfl_xor(l1, mk, 64);
    float M = fmaxf(m1, pm);
    l1 = l1 * ex2(m1 - M) + pl * ex2(pm - M);
    m1 = M;
    pm = __shfl_xor(m2, mk, 64); pl = __shfl_xor(l2, mk, 64);
    M = fmaxf(m2, pm);
    l2 = l2 * ex2(m2 - M) + pl * ex2(pm - M);
    m2 = M;
  }
  const float c2 = lamv * l1 / l2;

  f32x4 accv[8];
#pragma unroll
  for (int n = 0; n < 8; ++n) accv[n] = zero4;
  float dln = 0.f;

  STAGE_K(0, t0 * 64);
  STAGE_V(0, t0 * 64);
  __syncthreads();
  {
    int cur = 0;
    for (int t = t0; t <= qb; ++t, cur ^= 1) {
      if (t < qb) {
        STAGE_K(cur ^ 1, (t + 1) * 64);
        STAGE_V(cur ^ 1, (t + 1) * 64);
      }
      const int kb0 = t * 64;
      unsigned* pw = (unsigned*)&Pw[w][0];
      f32x4 s1v[4], s2v[4];
      QK_TILE(cur);
      const bool edge = (t == qb) || (qb >= 8 && t == t0);
      if (edge) dln += p2_probs<true>(s1v, s2v, m1, m2, c2, kb0, myq, lhi, l15, pw);
      else      dln += p2_probs<false>(s1v, s2v, m1, m2, c2, kb0, myq, lhi, l15, pw);
#pragma unroll
      for (int kc = 0; kc < 2; ++kc) {
        short8 pa = *(const short8*)(&Pw[w][l15 * 72 + kc * 32 + lhi * 8]);
#pragma unroll
        for (int n = 0; n < 8; ++n)
          accv[n] = MFMA16(pa, VFRAG(cur, n, kc * 4 + lhi), accv[n]);
      }
      __syncthreads();
    }
  }

  dln += __shfl_xor(dln, 16, 64);
  dln += __shfl_xor(dln, 32, 64);

  // ---------- epilogue: normalize, restage 64x128 tile in LDS, write FT ----------
  // LDS layout: chunk (mloc, cc) at elems (mloc*16 + (cc ^ (mloc&15)))*8  (cc = col>>3)
  bf16* L = &Kb[0][0];   // 16KB, reuse (all waves past last loop barrier)
#pragma unroll
  for (int r = 0; r < 4; ++r) {
    int srcq = lhi * 4 + r;
    int src = (lane & 48) | srcq;
    float dq = __shfl(dln, src, 64);
    float lq = __shfl(l1, src, 64);
    float rinv = 1.f / (dq + lq * 1e-6f);
    int mloc = w * 16 + srcq;
    int swz = mloc & 15;
#pragma unroll
    for (int n = 0; n < 8; ++n) {
      int cc = n * 2 + (l15 >> 3);
      L[(mloc * 16 + (cc ^ swz)) * 8 + (l15 & 7)] = __float2bfloat16(accv[n][r] * rinv);
    }
  }
  __syncthreads();
  // FT write: wave w handles frags f = p*4 + w (mf = p, kf = w); lane l = within-frag lane.
#pragma unroll
  for (int p = 0; p < 4; ++p) {
    int m = p * 16 + l15;                 // local row
    int ccr = w * 4 + lhi;                // local col chunk
    short8 v = *(const short8*)(&L[(m * 16 + (ccr ^ l15)) * 8]);
    size_t frag = (size_t)(qb * 4 + p) * 64 + h * 4 + w;
    *(short8*)(ATTft + frag * 512 + lane * 8) = v;
  }
#undef STAGE_K
#undef STAGE_V
#undef KFRAG
#undef VFRAG
#undef QK_TILE
}

// ================= launch =================
extern "C" void kernel_launch(void* const* d_in, const int* in_sizes, int n_in,
                              void* d_out, int out_size, void* d_ws, size_t ws_size,
                              hipStream_t stream)
{
  const float* x   = (const float*)d_in[0];
  const float* Wq  = (const float*)d_in[1];
  const float* Wk  = (const float*)d_in[2];
  const float* Wv  = (const float*)d_in[3];
  const float* Wo  = (const float*)d_in[4];
  const float* lam = (const float*)d_in[5];

  char* ws = (char*)d_ws;
  bf16* xbFT   = (bf16*)(ws);                       // FT 2048x2048  8 MB
  bf16* WqkvFT = (bf16*)(ws + 8ull  * (1u << 20));  // FT 3072x2048 12 MB
  bf16* WoFT   = (bf16*)(ws + 20ull * (1u << 20));  // FT 2048x2048  8 MB
  bf16* QKV    = (bf16*)(ws + 28ull * (1u << 20));  // [2048][3072] 12 MB
  bf16* ATTft  = (bf16*)(ws + 40ull * (1u << 20));  // FT 2048x2048  8 MB
  bf16* VT     = (bf16*)(ws + 48ull * (1u << 20));  // [512][2048]   2 MB

  prep_all<<<dim3(144, 32), 256, 0, stream>>>(x, Wq, Wk, Wv, Wo, xbFT, WqkvFT, WoFT);
  gemm_dd<0><<<dim3(24, 16), 256, 0, stream>>>(xbFT, WqkvFT, QKV, 2048, 3072, 2048);
  rope2<<<1280, 256, 0, stream>>>(QKV);
  transpose_v<<<dim3(32, 8), 256, 0, stream>>>(QKV, VT);
  diff_attn<<<dim3(32, 16), 256, 0, stream>>>(QKV, VT, lam, ATTft);
  gemm_dd<1><<<dim3(16, 16), 256, 0, stream>>>(ATTft, WoFT, d_out, 2048, 2048, 2048);
}

// Round 14
// 111.522 us; speedup vs baseline: 1.0781x; 1.0781x over previous
//
#include <hip/hip_runtime.h>
#include <hip/hip_bf16.h>
#include <stdint.h>

typedef __attribute__((ext_vector_type(8))) short short8;
typedef __attribute__((ext_vector_type(4))) float f32x4;
using bf16 = __hip_bfloat16;

#define MFMA16(a, b, c) __builtin_amdgcn_mfma_f32_16x16x32_bf16((a), (b), (c), 0, 0, 0)

#define GLOAD_LDS16(g, l) __builtin_amdgcn_global_load_lds( \
    (const __attribute__((address_space(1))) void*)(g),     \
    (__attribute__((address_space(3))) void*)(l), 16, 0, 0)

__device__ __forceinline__ unsigned packbf2(float lo, float hi) {
  unsigned r;
  asm("v_cvt_pk_bf16_f32 %0, %1, %2" : "=v"(r) : "v"(lo), "v"(hi));
  return r;
}
__device__ __forceinline__ float ex2(float x) {
  float r;
  asm("v_exp_f32 %0, %1" : "=v"(r) : "v"(x));
  return r;
}
__device__ __forceinline__ f32x4 vmax4(f32x4 a, f32x4 b) {
  f32x4 r;
  r[0] = fmaxf(a[0], b[0]); r[1] = fmaxf(a[1], b[1]);
  r[2] = fmaxf(a[2], b[2]); r[3] = fmaxf(a[3], b[3]);
  return r;
}

template <bool EDGE>
__device__ __forceinline__ void p1_update(const f32x4* sv, float& m, float& l,
                                          int kb0, int myq, int lhi) {
  f32x4 t4 = vmax4(vmax4(sv[0], sv[1]), vmax4(sv[2], sv[3]));
  float tm = fmaxf(fmaxf(t4[0], t4[1]), fmaxf(t4[2], t4[3]));
  float nm = fmaxf(m, tm);
  float sc = ex2(m - nm);
  float sum = 0.f;
#pragma unroll
  for (int nt = 0; nt < 4; ++nt) {
    float part = 0.f;
#pragma unroll
    for (int r = 0; r < 4; ++r) {
      float e = ex2(sv[nt][r] - nm);
      if (EDGE) {
        int key = kb0 + nt * 16 + lhi * 4 + r;
        bool ok = (key <= myq) && (key > myq - 512);
        e = ok ? e : 0.f;
      }
      part += e;
    }
    sum += part;
  }
  l = l * sc + sum;
  m = nm;
}

template <bool EDGE>
__device__ __forceinline__ float p2_probs(const f32x4* s1v, const f32x4* s2v,
                                          float m1, float m2, float c2,
                                          int kb0, int myq, int lhi, int l15,
                                          unsigned* pw) {
  float d0 = 0.f, d1 = 0.f;
#pragma unroll
  for (int nt = 0; nt < 4; ++nt) {
    float pr[4];
#pragma unroll
    for (int r = 0; r < 4; ++r) {
      float e1 = ex2(s1v[nt][r] - m1);
      float e2 = ex2(s2v[nt][r] - m2);
      float p = fmaf(-c2, e2, e1);
      p = fmaxf(p, 0.f);
      if (EDGE) {
        int key = kb0 + nt * 16 + lhi * 4 + r;
        bool ok = (key <= myq) && (key > myq - 512);
        p = ok ? p : 0.f;
      }
      pr[r] = p;
      if (r & 1) d1 += p; else d0 += p;
    }
    int pi = l15 * 36 + 8 * nt + 2 * lhi;
    pw[pi]     = packbf2(pr[0], pr[1]);
    pw[pi + 1] = packbf2(pr[2], pr[3]);
  }
  return d0 + d1;
}

// ================= fused prep: x f32->bf16 row-major + weights -> FT bf16 =================
// FT: element (n,k) at frag = (n>>4)*64 + (k>>5); lane = (n&15)+16*((k>>3)&3); elem = k&7.
__global__ __launch_bounds__(256) void prep_all(const float* __restrict__ x,
                                                const float* __restrict__ Wq,
                                                const float* __restrict__ Wk,
                                                const float* __restrict__ Wv,
                                                const float* __restrict__ Wo,
                                                bf16* __restrict__ xb,
                                                bf16* __restrict__ WqkvFT,
                                                bf16* __restrict__ WoFT)
{
  const int bx = blockIdx.x;
  const int tid = threadIdx.x;
  if (bx >= 80) {
    size_t i = ((size_t)(bx - 80) * 32 + blockIdx.y) * 2048 + tid * 8;
    const float* f = x + i;
    float4 a = *(const float4*)f;
    float4 b = *(const float4*)(f + 4);
    union { bf16 h[8]; short8 s; } u;
    u.h[0] = __float2bfloat16(a.x); u.h[1] = __float2bfloat16(a.y);
    u.h[2] = __float2bfloat16(a.z); u.h[3] = __float2bfloat16(a.w);
    u.h[4] = __float2bfloat16(b.x); u.h[5] = __float2bfloat16(b.y);
    u.h[6] = __float2bfloat16(b.z); u.h[7] = __float2bfloat16(b.w);
    *(short8*)(xb + i) = u.s;
    return;
  }
  const float* W;
  bf16* Wt;
  int N, n0;
  if (bx < 32)      { W = Wq; Wt = WqkvFT; N = 2048; n0 = bx * 64; }
  else if (bx < 40) { W = Wk; Wt = WqkvFT; N = 512;  n0 = 2048 + (bx - 32) * 64; }
  else if (bx < 48) { W = Wv; Wt = WqkvFT; N = 512;  n0 = 2560 + (bx - 40) * 64; }
  else              { W = Wo; Wt = WoFT;   N = 2048; n0 = (bx - 48) * 64; }
  const int nloc0 = (N == 512) ? (n0 - ((n0 >= 2560) ? 2560 : 2048)) : ((bx < 32 || bx >= 48) ? (n0 & 2047) : 0);
  const int k0 = blockIdx.y * 64;

  __shared__ bf16 t[64][72];
#pragma unroll
  for (int pass = 0; pass < 4; ++pass) {
    int r = pass * 16 + (tid >> 4);
    int c = (tid & 15) * 4;
    float4 v = *(const float4*)(W + (size_t)(k0 + r) * N + nloc0 + c);
    t[c + 0][r] = __float2bfloat16(v.x);
    t[c + 1][r] = __float2bfloat16(v.y);
    t[c + 2][r] = __float2bfloat16(v.z);
    t[c + 3][r] = __float2bfloat16(v.w);
  }
  __syncthreads();
#pragma unroll
  for (int pass = 0; pass < 2; ++pass) {
    int n = pass * 32 + (tid >> 3);
    int k8 = (tid & 7) * 8;
    int frag = ((n0 + n) >> 4) * 64 + ((k0 + k8) >> 5);
    int ln = (n & 15) + 16 * ((k8 >> 3) & 3);
    *(short8*)(Wt + (size_t)frag * 512 + ln * 8) = *(const short8*)(&t[n][k8]);
  }
}

// ================= GEMM: C = A(MxK row-major, LDS) @ Bft^T (FT, direct-to-VGPR) =================
// R12-proven hybrid. EPI=0: QKV epilogue fused (RoPE on Q/K tiles, V->VT transpose);
// EPI=1: plain f32 C write.
template <int EPI>
__global__ __launch_bounds__(256) void gemm_ft(const bf16* __restrict__ A,
                                               const bf16* __restrict__ Bft,
                                               void* __restrict__ C,
                                               bf16* __restrict__ VTp,
                                               int M, int N, int K)
{
  __shared__ __align__(16) bf16 As[4][128 * 32];

  const int tid  = threadIdx.x;
  const int lane = tid & 63;
  const int w    = tid >> 6;
  const int wmg  = (w >> 1) * 4;
  const int wng  = (w & 1) * 4;
  const int l15  = lane & 15;
  const int lhi  = lane >> 4;
  const int bm0  = blockIdx.y * 128;
  const int bn0  = blockIdx.x * 128;

  const int srow = lane >> 2;
  const int scol = ((lane & 3) ^ ((lane >> 3) & 3)) * 8;
  const int loff = l15 * 4 + (lhi ^ ((l15 >> 1) & 3));

  const int nkc = K >> 5;   // 64
  const bf16* bbase[4];
#pragma unroll
  for (int nt = 0; nt < 4; ++nt)
    bbase[nt] = Bft + ((size_t)((bn0 >> 4) + wng + nt) * nkc) * 512 + lane * 8;

  f32x4 acc[4][4];
  const f32x4 zero4 = {0.f, 0.f, 0.f, 0.f};
#pragma unroll
  for (int i = 0; i < 4; ++i)
#pragma unroll
    for (int j = 0; j < 4; ++j) acc[i][j] = zero4;

  short8 br0[4], br1[4], br2[4], br3[4];

#define GSTAGE_A(buf, kk)                                                          \
  { _Pragma("unroll")                                                              \
    for (int p = 0; p < 2; ++p) {                                                  \
      int s   = (p * 4 + w) * 64 + lane;                                           \
      int row = (p * 4 + w) * 16 + srow;                                           \
      GLOAD_LDS16(A + (size_t)(bm0 + row) * K + (kk) + scol, &As[buf][s * 8]);     \
    } }

#define BLOAD(breg, kc)                                                            \
  { _Pragma("unroll")                                                              \
    for (int nt = 0; nt < 4; ++nt) {                                               \
      asm volatile("global_load_dwordx4 %0, %1, off"                               \
                   : "=v"(breg[nt])                                                \
                   : "v"(bbase[nt] + (size_t)(kc) * 512)                           \
                   : "memory");                                                    \
    } }

#define KSTEP(aslot, breg, wcn, ...)                                               \
  {                                                                                \
    asm volatile("s_waitcnt vmcnt(" #wcn ")" ::: "memory");                        \
    __builtin_amdgcn_s_barrier();                                                  \
    __builtin_amdgcn_sched_barrier(0);                                             \
    __VA_ARGS__                                                                    \
    short8 a_[4];                                                                  \
    _Pragma("unroll")                                                              \
    for (int mt = 0; mt < 4; ++mt)                                                 \
      a_[mt] = *(const short8*)(&As[aslot][((wmg + mt) * 64 + loff) * 8]);         \
    _Pragma("unroll")                                                              \
    for (int mt = 0; mt < 4; ++mt)                                                 \
      _Pragma("unroll")                                                            \
      for (int nt = 0; nt < 4; ++nt)                                               \
        acc[mt][nt] = MFMA16(a_[mt], breg[nt], acc[mt][nt]);                       \
  }

  GSTAGE_A(0, 0);  BLOAD(br0, 0);
  GSTAGE_A(1, 32); BLOAD(br1, 1);
  GSTAGE_A(2, 64); BLOAD(br2, 2);

  for (int t = 0; t < nkc - 4; t += 4) {
    KSTEP(0, br0, 12, GSTAGE_A(3, (t + 3) * 32); BLOAD(br3, t + 3);)
    KSTEP(1, br1, 12, GSTAGE_A(0, (t + 4) * 32); BLOAD(br0, t + 4);)
    KSTEP(2, br2, 12, GSTAGE_A(1, (t + 5) * 32); BLOAD(br1, t + 5);)
    KSTEP(3, br3, 12, GSTAGE_A(2, (t + 6) * 32); BLOAD(br2, t + 6);)
  }
  KSTEP(0, br0, 12, GSTAGE_A(3, (nkc - 1) * 32); BLOAD(br3, nkc - 1);)
  KSTEP(1, br1, 12, )
  KSTEP(2, br2, 6, )
  KSTEP(3, br3, 0, )
#undef GSTAGE_A
#undef BLOAD
#undef KSTEP

  if (EPI == 1) {
#pragma unroll
    for (int mt = 0; mt < 4; ++mt) {
      int row0 = bm0 + (wmg + mt) * 16 + lhi * 4;
#pragma unroll
      for (int nt = 0; nt < 4; ++nt) {
        int col = bn0 + (wng + nt) * 16 + l15;
#pragma unroll
        for (int r = 0; r < 4; ++r)
          ((float*)C)[(size_t)(row0 + r) * N + col] = acc[mt][nt][r];
      }
    }
    return;
  }

  // ---------- EPI=0: fused QKV epilogue ----------
  __syncthreads();   // drain ring: safe to reuse As
  if (bn0 < 2560) {
    // RoPE path (Q tiles: scale 0.125*log2e; K tiles: scale 1)
    float* Lf = (float*)&As[0][0];       // [64][128] f32 = 32KB
    const float scale = (bn0 < 2048) ? 0.180336880111120f : 1.0f;
#pragma unroll
    for (int c = 0; c < 2; ++c) {
      if ((w >> 1) == c) {               // writers: waves covering rows c*64..c*64+63
#pragma unroll
        for (int mt = 0; mt < 4; ++mt)
#pragma unroll
          for (int nt = 0; nt < 4; ++nt) {
            int col = (wng + nt) * 16 + l15;
#pragma unroll
            for (int r = 0; r < 4; ++r)
              Lf[(mt * 16 + lhi * 4 + r) * 128 + col] = acc[mt][nt][r];
          }
      }
      __syncthreads();
      {
        int rloc = tid >> 2;
        int dg = (tid & 3) * 16;
        int s = bm0 + c * 64 + rloc;
        bf16* orow = (bf16*)C + (size_t)s * N + bn0;
        union { bf16 h[16]; short8 v[2]; } o1, o2;
#pragma unroll
        for (int e = 0; e < 16; ++e) {
          int d = dg + e;
          float inv = __expf(-(float)d * (9.210340371976184f / 64.0f));
          float ang = (float)s * inv;
          float cs = __cosf(ang), sn = __sinf(ang);
          float x1 = Lf[rloc * 128 + d];
          float x2 = Lf[rloc * 128 + d + 64];
          o1.h[e] = __float2bfloat16((x1 * cs - x2 * sn) * scale);
          o2.h[e] = __float2bfloat16((x2 * cs + x1 * sn) * scale);
        }
        *(short8*)(orow + dg)      = o1.v[0];
        *(short8*)(orow + dg + 8)  = o1.v[1];
        *(short8*)(orow + dg + 64) = o2.v[0];
        *(short8*)(orow + dg + 72) = o2.v[1];
      }
      __syncthreads();
    }
  } else {
    // V tiles: write transposed into VT only (QKV V-region never consumed)
    bf16* Lb = &As[0][0];                // [64][136] bf16 = 17.4KB
#pragma unroll
    for (int cc = 0; cc < 2; ++cc) {
      if ((w & 1) == cc) {               // writers: waves covering cols cc*64..cc*64+63
#pragma unroll
        for (int mt = 0; mt < 4; ++mt)
#pragma unroll
          for (int nt = 0; nt < 4; ++nt) {
            int colloc = nt * 16 + l15;  // 0..63 within chunk
#pragma unroll
            for (int r = 0; r < 4; ++r) {
              int key = (wmg + mt) * 16 + lhi * 4 + r;
              Lb[colloc * 136 + key] = __float2bfloat16(acc[mt][nt][r]);
            }
          }
      }
      __syncthreads();
      {
        int dl = tid >> 2;               // dim-local 0..63
        int kq = (tid & 3) * 32;         // key quarter
        int dim = (bn0 - 2560) + cc * 64 + dl;
        bf16* vrow = VTp + (size_t)dim * 2048 + bm0 + kq;
#pragma unroll
        for (int j = 0; j < 4; ++j)
          *(short8*)(vrow + j * 8) = *(const short8*)(&Lb[dl * 136 + kq + j * 8]);
      }
      __syncthreads();
    }
  }
}

// ================= Differential sliding-window attention (swapped-QK, log2 domain) =================
__global__ __launch_bounds__(256) void diff_attn(const bf16* __restrict__ QKV,
                                                 const bf16* __restrict__ VT,
                                                 const float* __restrict__ lam,
                                                 bf16* __restrict__ O)
{
  __shared__ __align__(16) bf16 Kb[2][64 * 128];
  __shared__ __align__(16) bf16 Vb[2][128 * 64];
  __shared__ __align__(16) bf16 Pw[4][16 * 72];

  const int qb   = blockIdx.x;
  const int h    = blockIdx.y;
  const int kvh  = h >> 2;
  const int tid  = threadIdx.x;
  const int lane = tid & 63;
  const int w    = tid >> 6;
  const int l15  = lane & 15;
  const int lhi  = lane >> 4;
  const int qg   = qb * 64 + w * 16;
  const int myq  = qg + l15;
  const float lamv = lam[h];

  const bf16* Kg = QKV + 2048 + (size_t)kvh * 128;
  const bf16* Vg = VT + (size_t)kvh * 128 * 2048;

  short8 qf[4];
  {
    const bf16* qrow = QKV + (size_t)myq * 3072 + h * 128;
#pragma unroll
    for (int c = 0; c < 4; ++c)
      qf[c] = *(const short8*)(qrow + c * 32 + lhi * 8);
  }

  const int t0 = (qb >= 8) ? (qb - 8) : 0;

#define STAGE_K(buf, kbase)                                                     \
  {                                                                             \
    _Pragma("unroll")                                                           \
    for (int p = 0; p < 4; ++p) {                                               \
      int c = p * 256 + tid;                                                    \
      int r = c >> 4, q = c & 15;                                               \
      GLOAD_LDS16(Kg + (size_t)((kbase) + r) * 3072 + ((q ^ (r & 7)) * 8),      \
                  &Kb[buf][c * 8]);                                             \
    }                                                                           \
  }
#define STAGE_V(buf, kbase)                                                     \
  {                                                                             \
    _Pragma("unroll")                                                           \
    for (int p = 0; p < 4; ++p) {                                               \
      int c = p * 256 + tid;                                                    \
      int d = c >> 3, q = c & 7;                                                \
      GLOAD_LDS16(Vg + (size_t)d * 2048 + (kbase) + ((q ^ (d & 7)) * 8),        \
                  &Vb[buf][c * 8]);                                             \
    }                                                                           \
  }
#define KFRAG(buf, nt, qc) \
  (*(const short8*)(&Kb[buf][(((nt) * 16 + l15) * 16 + ((qc) ^ (((nt) * 16 + l15) & 7))) * 8]))
#define VFRAG(buf, n, qc) \
  (*(const short8*)(&Vb[buf][(((n) * 16 + l15) * 8 + ((qc) ^ (((n) * 16 + l15) & 7))) * 8]))
#define QK_TILE(cur)                                            \
  _Pragma("unroll")                                             \
  for (int nt = 0; nt < 4; ++nt) {                              \
    f32x4 s1 = zero4, s2 = zero4;                               \
    s1 = MFMA16(KFRAG(cur, nt, lhi),      qf[0], s1);           \
    s1 = MFMA16(KFRAG(cur, nt, 4 + lhi),  qf[1], s1);           \
    s2 = MFMA16(KFRAG(cur, nt, 8 + lhi),  qf[2], s2);           \
    s2 = MFMA16(KFRAG(cur, nt, 12 + lhi), qf[3], s2);           \
    s1v[nt] = s1; s2v[nt] = s2;                                 \
  }

  const f32x4 zero4 = {0.f, 0.f, 0.f, 0.f};

  float m1 = -1e30f, l1 = 0.f, m2 = -1e30f, l2 = 0.f;
  STAGE_K(0, t0 * 64);
  __syncthreads();
  {
    int cur = 0;
    for (int t = t0; t <= qb; ++t, cur ^= 1) {
      if (t < qb) STAGE_K(cur ^ 1, (t + 1) * 64);
      const int kb0 = t * 64;
      f32x4 s1v[4], s2v[4];
      QK_TILE(cur);
      const bool edge = (t == qb) || (qb >= 8 && t == t0);
      if (edge) {
        p1_update<true>(s1v, m1, l1, kb0, myq, lhi);
        p1_update<true>(s2v, m2, l2, kb0, myq, lhi);
      } else {
        p1_update<false>(s1v, m1, l1, kb0, myq, lhi);
        p1_update<false>(s2v, m2, l2, kb0, myq, lhi);
      }
      __syncthreads();
    }
  }

#pragma unroll
  for (int mk = 16; mk <= 32; mk <<= 1) {
    float pm = __shfl_xor(m1, mk, 64), pl = __shfl_xor(l1, mk, 64);
    float M = fmaxf(m1, pm);
    l1 = l1 * ex2(m1 - M) + pl * ex2(pm - M);
    m1 = M;
    pm = __shfl_xor(m2, mk, 64); pl = __shfl_xor(l2, mk, 64);
    M = fmaxf(m2, pm);
    l2 = l2 * ex2(m2 - M) + pl * ex2(pm - M);
    m2 = M;
  }
  const float c2 = lamv * l1 / l2;

  f32x4 accv[8];
#pragma unroll
  for (int n = 0; n < 8; ++n) accv[n] = zero4;
  float dln = 0.f;

  STAGE_K(0, t0 * 64);
  STAGE_V(0, t0 * 64);
  __syncthreads();
  {
    int cur = 0;
    for (int t = t0; t <= qb; ++t, cur ^= 1) {
      if (t < qb) {
        STAGE_K(cur ^ 1, (t + 1) * 64);
        STAGE_V(cur ^ 1, (t + 1) * 64);
      }
      const int kb0 = t * 64;
      unsigned* pw = (unsigned*)&Pw[w][0];
      f32x4 s1v[4], s2v[4];
      QK_TILE(cur);
      const bool edge = (t == qb) || (qb >= 8 && t == t0);
      if (edge) dln += p2_probs<true>(s1v, s2v, m1, m2, c2, kb0, myq, lhi, l15, pw);
      else      dln += p2_probs<false>(s1v, s2v, m1, m2, c2, kb0, myq, lhi, l15, pw);
#pragma unroll
      for (int kc = 0; kc < 2; ++kc) {
        short8 pa = *(const short8*)(&Pw[w][l15 * 72 + kc * 32 + lhi * 8]);
#pragma unroll
        for (int n = 0; n < 8; ++n)
          accv[n] = MFMA16(pa, VFRAG(cur, n, kc * 4 + lhi), accv[n]);
      }
      __syncthreads();
    }
  }

  dln += __shfl_xor(dln, 16, 64);
  dln += __shfl_xor(dln, 32, 64);

#pragma unroll
  for (int r = 0; r < 4; ++r) {
    int srcq = lhi * 4 + r;
    int src = (lane & 48) | srcq;
    float dq = __shfl(dln, src, 64);
    float lq = __shfl(l1, src, 64);
    float rinv = 1.f / (dq + lq * 1e-6f);
    int qo = qg + srcq;
#pragma unroll
    for (int n = 0; n < 8; ++n) {
      O[(size_t)qo * 2048 + h * 128 + n * 16 + l15] =
          __float2bfloat16(accv[n][r] * rinv);
    }
  }
#undef STAGE_K
#undef STAGE_V
#undef KFRAG
#undef VFRAG
#undef QK_TILE
}

// ================= launch =================
extern "C" void kernel_launch(void* const* d_in, const int* in_sizes, int n_in,
                              void* d_out, int out_size, void* d_ws, size_t ws_size,
                              hipStream_t stream)
{
  const float* x   = (const float*)d_in[0];
  const float* Wq  = (const float*)d_in[1];
  const float* Wk  = (const float*)d_in[2];
  const float* Wv  = (const float*)d_in[3];
  const float* Wo  = (const float*)d_in[4];
  const float* lam = (const float*)d_in[5];

  char* ws = (char*)d_ws;
  bf16* xb     = (bf16*)(ws);                       // [2048][2048]  8 MB
  bf16* WqkvFT = (bf16*)(ws + 8ull  * (1u << 20));  // FT 3072x2048 12 MB
  bf16* WoFT   = (bf16*)(ws + 20ull * (1u << 20));  // FT 2048x2048  8 MB
  bf16* QKV    = (bf16*)(ws + 28ull * (1u << 20));  // [2048][3072] 12 MB (V region unused)
  bf16* ATT    = (bf16*)(ws + 40ull * (1u << 20));  // [2048][2048]  8 MB
  bf16* VT     = (bf16*)(ws + 48ull * (1u << 20));  // [512][2048]   2 MB

  prep_all<<<dim3(144, 32), 256, 0, stream>>>(x, Wq, Wk, Wv, Wo, xb, WqkvFT, WoFT);
  gemm_ft<0><<<dim3(24, 16), 256, 0, stream>>>(xb, WqkvFT, QKV, VT, 2048, 3072, 2048);
  diff_attn<<<dim3(32, 16), 256, 0, stream>>>(QKV, VT, lam, ATT);
  gemm_ft<1><<<dim3(16, 16), 256, 0, stream>>>(ATT, WoFT, d_out, nullptr, 2048, 2048, 2048);
}

// Round 15
// 110.874 us; speedup vs baseline: 1.0844x; 1.0058x over previous
//
#include <hip/hip_runtime.h>
#include <hip/hip_bf16.h>
#include <stdint.h>

typedef __attribute__((ext_vector_type(8))) short short8;
typedef __attribute__((ext_vector_type(4))) float f32x4;
using bf16 = __hip_bfloat16;

#define MFMA16(a, b, c) __builtin_amdgcn_mfma_f32_16x16x32_bf16((a), (b), (c), 0, 0, 0)

#define GLOAD_LDS16(g, l) __builtin_amdgcn_global_load_lds( \
    (const __attribute__((address_space(1))) void*)(g),     \
    (__attribute__((address_space(3))) void*)(l), 16, 0, 0)

__device__ __forceinline__ unsigned packbf2(float lo, float hi) {
  unsigned r;
  asm("v_cvt_pk_bf16_f32 %0, %1, %2" : "=v"(r) : "v"(lo), "v"(hi));
  return r;
}
__device__ __forceinline__ float ex2(float x) {
  float r;
  asm("v_exp_f32 %0, %1" : "=v"(r) : "v"(x));
  return r;
}
__device__ __forceinline__ f32x4 vmax4(f32x4 a, f32x4 b) {
  f32x4 r;
  r[0] = fmaxf(a[0], b[0]); r[1] = fmaxf(a[1], b[1]);
  r[2] = fmaxf(a[2], b[2]); r[3] = fmaxf(a[3], b[3]);
  return r;
}

template <bool EDGE>
__device__ __forceinline__ void p1_update(const f32x4* sv, float& m, float& l,
                                          int kb0, int myq, int lhi) {
  f32x4 t4 = vmax4(vmax4(sv[0], sv[1]), vmax4(sv[2], sv[3]));
  float tm = fmaxf(fmaxf(t4[0], t4[1]), fmaxf(t4[2], t4[3]));
  float nm = fmaxf(m, tm);
  float sc = ex2(m - nm);
  float sum = 0.f;
#pragma unroll
  for (int nt = 0; nt < 4; ++nt) {
    float part = 0.f;
#pragma unroll
    for (int r = 0; r < 4; ++r) {
      float e = ex2(sv[nt][r] - nm);
      if (EDGE) {
        int key = kb0 + nt * 16 + lhi * 4 + r;
        bool ok = (key <= myq) && (key > myq - 512);
        e = ok ? e : 0.f;
      }
      part += e;
    }
    sum += part;
  }
  l = l * sc + sum;
  m = nm;
}

template <bool EDGE>
__device__ __forceinline__ float p2_probs(const f32x4* s1v, const f32x4* s2v,
                                          float m1, float m2, float c2,
                                          int kb0, int myq, int lhi, int l15,
                                          unsigned* pw) {
  float d0 = 0.f, d1 = 0.f;
#pragma unroll
  for (int nt = 0; nt < 4; ++nt) {
    float pr[4];
#pragma unroll
    for (int r = 0; r < 4; ++r) {
      float e1 = ex2(s1v[nt][r] - m1);
      float e2 = ex2(s2v[nt][r] - m2);
      float p = fmaf(-c2, e2, e1);
      p = fmaxf(p, 0.f);
      if (EDGE) {
        int key = kb0 + nt * 16 + lhi * 4 + r;
        bool ok = (key <= myq) && (key > myq - 512);
        p = ok ? p : 0.f;
      }
      pr[r] = p;
      if (r & 1) d1 += p; else d0 += p;
    }
    int pi = l15 * 36 + 8 * nt + 2 * lhi;
    pw[pi]     = packbf2(pr[0], pr[1]);
    pw[pi + 1] = packbf2(pr[2], pr[3]);
  }
  return d0 + d1;
}

// ================= fused prep: x f32->bf16 row-major + weights -> FT bf16 =================
__global__ __launch_bounds__(256) void prep_all(const float* __restrict__ x,
                                                const float* __restrict__ Wq,
                                                const float* __restrict__ Wk,
                                                const float* __restrict__ Wv,
                                                const float* __restrict__ Wo,
                                                bf16* __restrict__ xb,
                                                bf16* __restrict__ WqkvFT,
                                                bf16* __restrict__ WoFT)
{
  const int bx = blockIdx.x;
  const int tid = threadIdx.x;
  if (bx >= 80) {
    size_t i = ((size_t)(bx - 80) * 32 + blockIdx.y) * 2048 + tid * 8;
    const float* f = x + i;
    float4 a = *(const float4*)f;
    float4 b = *(const float4*)(f + 4);
    union { bf16 h[8]; short8 s; } u;
    u.h[0] = __float2bfloat16(a.x); u.h[1] = __float2bfloat16(a.y);
    u.h[2] = __float2bfloat16(a.z); u.h[3] = __float2bfloat16(a.w);
    u.h[4] = __float2bfloat16(b.x); u.h[5] = __float2bfloat16(b.y);
    u.h[6] = __float2bfloat16(b.z); u.h[7] = __float2bfloat16(b.w);
    *(short8*)(xb + i) = u.s;
    return;
  }
  const float* W;
  bf16* Wt;
  int N, n0;
  if (bx < 32)      { W = Wq; Wt = WqkvFT; N = 2048; n0 = bx * 64; }
  else if (bx < 40) { W = Wk; Wt = WqkvFT; N = 512;  n0 = 2048 + (bx - 32) * 64; }
  else if (bx < 48) { W = Wv; Wt = WqkvFT; N = 512;  n0 = 2560 + (bx - 40) * 64; }
  else              { W = Wo; Wt = WoFT;   N = 2048; n0 = (bx - 48) * 64; }
  const int nloc0 = (N == 512) ? (n0 - ((n0 >= 2560) ? 2560 : 2048)) : ((bx < 32 || bx >= 48) ? (n0 & 2047) : 0);
  const int k0 = blockIdx.y * 64;

  __shared__ bf16 t[64][72];
#pragma unroll
  for (int pass = 0; pass < 4; ++pass) {
    int r = pass * 16 + (tid >> 4);
    int c = (tid & 15) * 4;
    float4 v = *(const float4*)(W + (size_t)(k0 + r) * N + nloc0 + c);
    t[c + 0][r] = __float2bfloat16(v.x);
    t[c + 1][r] = __float2bfloat16(v.y);
    t[c + 2][r] = __float2bfloat16(v.z);
    t[c + 3][r] = __float2bfloat16(v.w);
  }
  __syncthreads();
#pragma unroll
  for (int pass = 0; pass < 2; ++pass) {
    int n = pass * 32 + (tid >> 3);
    int k8 = (tid & 7) * 8;
    int frag = ((n0 + n) >> 4) * 64 + ((k0 + k8) >> 5);
    int ln = (n & 15) + 16 * ((k8 >> 3) & 3);
    *(short8*)(Wt + (size_t)frag * 512 + ln * 8) = *(const short8*)(&t[n][k8]);
  }
}

// ================= GEMM: C = A(MxK row-major, LDS) @ Bft^T (FT, direct-to-VGPR) =================
// R12-proven hybrid + XCD-swizzled block mapping.
// EPI=0: QKV epilogue fused (RoPE Q/K, V->VT). EPI=1: plain f32 write.
template <int EPI>
__global__ __launch_bounds__(256) void gemm_ft(const bf16* __restrict__ A,
                                               const bf16* __restrict__ Bft,
                                               void* __restrict__ C,
                                               bf16* __restrict__ VTp,
                                               int M, int N, int K)
{
  __shared__ __align__(16) bf16 As[4][128 * 32];

  const int tid  = threadIdx.x;
  const int lane = tid & 63;
  const int w    = tid >> 6;
  const int wmg  = (w >> 1) * 4;
  const int wng  = (w & 1) * 4;
  const int l15  = lane & 15;
  const int lhi  = lane >> 4;

  // XCD swizzle (nwg % 8 == 0 for all grids used)
  const int nbx = gridDim.x;
  const int lb  = blockIdx.y * nbx + blockIdx.x;
  const int nwg = nbx * gridDim.y;
  const int lsw = (lb & 7) * (nwg >> 3) + (lb >> 3);
  const int bm0 = (lsw / nbx) * 128;
  const int bn0 = (lsw % nbx) * 128;

  const int srow = lane >> 2;
  const int scol = ((lane & 3) ^ ((lane >> 3) & 3)) * 8;
  const int loff = l15 * 4 + (lhi ^ ((l15 >> 1) & 3));

  const int nkc = K >> 5;   // 64
  const bf16* bbase[4];
#pragma unroll
  for (int nt = 0; nt < 4; ++nt)
    bbase[nt] = Bft + ((size_t)((bn0 >> 4) + wng + nt) * nkc) * 512 + lane * 8;

  f32x4 acc[4][4];
  const f32x4 zero4 = {0.f, 0.f, 0.f, 0.f};
#pragma unroll
  for (int i = 0; i < 4; ++i)
#pragma unroll
    for (int j = 0; j < 4; ++j) acc[i][j] = zero4;

  short8 br0[4], br1[4], br2[4], br3[4];

#define GSTAGE_A(buf, kk)                                                          \
  { _Pragma("unroll")                                                              \
    for (int p = 0; p < 2; ++p) {                                                  \
      int s   = (p * 4 + w) * 64 + lane;                                           \
      int row = (p * 4 + w) * 16 + srow;                                           \
      GLOAD_LDS16(A + (size_t)(bm0 + row) * K + (kk) + scol, &As[buf][s * 8]);     \
    } }

#define BLOAD(breg, kc)                                                            \
  { _Pragma("unroll")                                                              \
    for (int nt = 0; nt < 4; ++nt) {                                               \
      asm volatile("global_load_dwordx4 %0, %1, off"                               \
                   : "=v"(breg[nt])                                                \
                   : "v"(bbase[nt] + (size_t)(kc) * 512)                           \
                   : "memory");                                                    \
    } }

#define KSTEP(aslot, breg, wcn, ...)                                               \
  {                                                                                \
    asm volatile("s_waitcnt vmcnt(" #wcn ")" ::: "memory");                        \
    __builtin_amdgcn_s_barrier();                                                  \
    __builtin_amdgcn_sched_barrier(0);                                             \
    __VA_ARGS__                                                                    \
    short8 a_[4];                                                                  \
    _Pragma("unroll")                                                              \
    for (int mt = 0; mt < 4; ++mt)                                                 \
      a_[mt] = *(const short8*)(&As[aslot][((wmg + mt) * 64 + loff) * 8]);         \
    _Pragma("unroll")                                                              \
    for (int mt = 0; mt < 4; ++mt)                                                 \
      _Pragma("unroll")                                                            \
      for (int nt = 0; nt < 4; ++nt)                                               \
        acc[mt][nt] = MFMA16(a_[mt], breg[nt], acc[mt][nt]);                       \
  }

  GSTAGE_A(0, 0);  BLOAD(br0, 0);
  GSTAGE_A(1, 32); BLOAD(br1, 1);
  GSTAGE_A(2, 64); BLOAD(br2, 2);

  for (int t = 0; t < nkc - 4; t += 4) {
    KSTEP(0, br0, 12, GSTAGE_A(3, (t + 3) * 32); BLOAD(br3, t + 3);)
    KSTEP(1, br1, 12, GSTAGE_A(0, (t + 4) * 32); BLOAD(br0, t + 4);)
    KSTEP(2, br2, 12, GSTAGE_A(1, (t + 5) * 32); BLOAD(br1, t + 5);)
    KSTEP(3, br3, 12, GSTAGE_A(2, (t + 6) * 32); BLOAD(br2, t + 6);)
  }
  KSTEP(0, br0, 12, GSTAGE_A(3, (nkc - 1) * 32); BLOAD(br3, nkc - 1);)
  KSTEP(1, br1, 12, )
  KSTEP(2, br2, 6, )
  KSTEP(3, br3, 0, )
#undef GSTAGE_A
#undef BLOAD
#undef KSTEP

  if (EPI == 1) {
#pragma unroll
    for (int mt = 0; mt < 4; ++mt) {
      int row0 = bm0 + (wmg + mt) * 16 + lhi * 4;
#pragma unroll
      for (int nt = 0; nt < 4; ++nt) {
        int col = bn0 + (wng + nt) * 16 + l15;
#pragma unroll
        for (int r = 0; r < 4; ++r)
          ((float*)C)[(size_t)(row0 + r) * N + col] = acc[mt][nt][r];
      }
    }
    return;
  }

  // ---------- EPI=0: fused QKV epilogue ----------
  __syncthreads();
  if (bn0 < 2560) {
    float* Lf = (float*)&As[0][0];       // [64][128] f32 = 32KB
    const float scale = (bn0 < 2048) ? 0.180336880111120f : 1.0f;
#pragma unroll
    for (int c = 0; c < 2; ++c) {
      if ((w >> 1) == c) {
#pragma unroll
        for (int mt = 0; mt < 4; ++mt)
#pragma unroll
          for (int nt = 0; nt < 4; ++nt) {
            int col = (wng + nt) * 16 + l15;
#pragma unroll
            for (int r = 0; r < 4; ++r)
              Lf[(mt * 16 + lhi * 4 + r) * 128 + col] = acc[mt][nt][r];
          }
      }
      __syncthreads();
      {
        int rloc = tid >> 2;
        int dg = (tid & 3) * 16;
        int s = bm0 + c * 64 + rloc;
        bf16* orow = (bf16*)C + (size_t)s * N + bn0;
        union { bf16 h[16]; short8 v[2]; } o1, o2;
#pragma unroll
        for (int e = 0; e < 16; ++e) {
          int d = dg + e;
          float inv = __expf(-(float)d * (9.210340371976184f / 64.0f));
          float ang = (float)s * inv;
          float cs = __cosf(ang), sn = __sinf(ang);
          float x1 = Lf[rloc * 128 + d];
          float x2 = Lf[rloc * 128 + d + 64];
          o1.h[e] = __float2bfloat16((x1 * cs - x2 * sn) * scale);
          o2.h[e] = __float2bfloat16((x2 * cs + x1 * sn) * scale);
        }
        *(short8*)(orow + dg)      = o1.v[0];
        *(short8*)(orow + dg + 8)  = o1.v[1];
        *(short8*)(orow + dg + 64) = o2.v[0];
        *(short8*)(orow + dg + 72) = o2.v[1];
      }
      __syncthreads();
    }
  } else {
    bf16* Lb = &As[0][0];                // [64][136] bf16
#pragma unroll
    for (int cc = 0; cc < 2; ++cc) {
      if ((w & 1) == cc) {
#pragma unroll
        for (int mt = 0; mt < 4; ++mt)
#pragma unroll
          for (int nt = 0; nt < 4; ++nt) {
            int colloc = nt * 16 + l15;
#pragma unroll
            for (int r = 0; r < 4; ++r) {
              int key = (wmg + mt) * 16 + lhi * 4 + r;
              Lb[colloc * 136 + key] = __float2bfloat16(acc[mt][nt][r]);
            }
          }
      }
      __syncthreads();
      {
        int dl = tid >> 2;
        int kq = (tid & 3) * 32;
        int dim = (bn0 - 2560) + cc * 64 + dl;
        bf16* vrow = VTp + (size_t)dim * 2048 + bm0 + kq;
#pragma unroll
        for (int j = 0; j < 4; ++j)
          *(short8*)(vrow + j * 8) = *(const short8*)(&Lb[dl * 136 + kq + j * 8]);
      }
      __syncthreads();
    }
  }
}

// ================= Differential sliding-window attention (swapped-QK, log2 domain) =================
// Counted-vmcnt tile pipeline: issue stage(t+1) -> vmcnt(N) -> barrier -> compute -> barrier.
__global__ __launch_bounds__(256) void diff_attn(const bf16* __restrict__ QKV,
                                                 const bf16* __restrict__ VT,
                                                 const float* __restrict__ lam,
                                                 bf16* __restrict__ O)
{
  __shared__ __align__(16) bf16 Kb[2][64 * 128];
  __shared__ __align__(16) bf16 Vb[2][128 * 64];
  __shared__ __align__(16) bf16 Pw[4][16 * 72];

  // XCD swizzle: 512 blocks -> 64 consecutive per XCD (2 heads' K/V per L2)
  const int lb  = blockIdx.y * 32 + blockIdx.x;
  const int lsw = (lb & 7) * 64 + (lb >> 3);
  const int qb  = lsw & 31;
  const int h   = lsw >> 5;

  const int kvh  = h >> 2;
  const int tid  = threadIdx.x;
  const int lane = tid & 63;
  const int w    = tid >> 6;
  const int l15  = lane & 15;
  const int lhi  = lane >> 4;
  const int qg   = qb * 64 + w * 16;
  const int myq  = qg + l15;
  const float lamv = lam[h];

  const bf16* Kg = QKV + 2048 + (size_t)kvh * 128;
  const bf16* Vg = VT + (size_t)kvh * 128 * 2048;

  short8 qf[4];
  {
    const bf16* qrow = QKV + (size_t)myq * 3072 + h * 128;
#pragma unroll
    for (int c = 0; c < 4; ++c)
      qf[c] = *(const short8*)(qrow + c * 32 + lhi * 8);
  }

  const int t0 = (qb >= 8) ? (qb - 8) : 0;

#define STAGE_K(buf, kbase)                                                     \
  {                                                                             \
    _Pragma("unroll")                                                           \
    for (int p = 0; p < 4; ++p) {                                               \
      int c = p * 256 + tid;                                                    \
      int r = c >> 4, q = c & 15;                                               \
      GLOAD_LDS16(Kg + (size_t)((kbase) + r) * 3072 + ((q ^ (r & 7)) * 8),      \
                  &Kb[buf][c * 8]);                                             \
    }                                                                           \
  }
#define STAGE_V(buf, kbase)                                                     \
  {                                                                             \
    _Pragma("unroll")                                                           \
    for (int p = 0; p < 4; ++p) {                                               \
      int c = p * 256 + tid;                                                    \
      int d = c >> 3, q = c & 7;                                                \
      GLOAD_LDS16(Vg + (size_t)d * 2048 + (kbase) + ((q ^ (d & 7)) * 8),        \
                  &Vb[buf][c * 8]);                                             \
    }                                                                           \
  }
#define KFRAG(buf, nt, qc) \
  (*(const short8*)(&Kb[buf][(((nt) * 16 + l15) * 16 + ((qc) ^ (((nt) * 16 + l15) & 7))) * 8]))
#define VFRAG(buf, n, qc) \
  (*(const short8*)(&Vb[buf][(((n) * 16 + l15) * 8 + ((qc) ^ (((n) * 16 + l15) & 7))) * 8]))
#define QK_TILE(cur)                                            \
  _Pragma("unroll")                                             \
  for (int nt = 0; nt < 4; ++nt) {                              \
    f32x4 s1 = zero4, s2 = zero4;                               \
    s1 = MFMA16(KFRAG(cur, nt, lhi),      qf[0], s1);           \
    s1 = MFMA16(KFRAG(cur, nt, 4 + lhi),  qf[1], s1);           \
    s2 = MFMA16(KFRAG(cur, nt, 8 + lhi),  qf[2], s2);           \
    s2 = MFMA16(KFRAG(cur, nt, 12 + lhi), qf[3], s2);           \
    s1v[nt] = s1; s2v[nt] = s2;                                 \
  }

  const f32x4 zero4 = {0.f, 0.f, 0.f, 0.f};

  // ---------- pass 1: stats, counted-vmcnt pipeline ----------
  float m1 = -1e30f, l1 = 0.f, m2 = -1e30f, l2 = 0.f;
  STAGE_K(0, t0 * 64);
  asm volatile("s_waitcnt vmcnt(0)" ::: "memory");
  __builtin_amdgcn_s_barrier();
  {
    int cur = 0;
    for (int t = t0; t <= qb; ++t, cur ^= 1) {
      if (t < qb) {
        STAGE_K(cur ^ 1, (t + 1) * 64);
        asm volatile("s_waitcnt vmcnt(4)" ::: "memory");
      } else {
        asm volatile("s_waitcnt vmcnt(0)" ::: "memory");
      }
      __builtin_amdgcn_s_barrier();
      __builtin_amdgcn_sched_barrier(0);
      const int kb0 = t * 64;
      f32x4 s1v[4], s2v[4];
      QK_TILE(cur);
      const bool edge = (t == qb) || (qb >= 8 && t == t0);
      if (edge) {
        p1_update<true>(s1v, m1, l1, kb0, myq, lhi);
        p1_update<true>(s2v, m2, l2, kb0, myq, lhi);
      } else {
        p1_update<false>(s1v, m1, l1, kb0, myq, lhi);
        p1_update<false>(s2v, m2, l2, kb0, myq, lhi);
      }
      __builtin_amdgcn_s_barrier();
    }
  }

#pragma unroll
  for (int mk = 16; mk <= 32; mk <<= 1) {
    float pm = __shfl_xor(m1, mk, 64), pl = __shfl_xor(l1, mk, 64);
    float M = fmaxf(m1, pm);
    l1 = l1 * ex2(m1 - M) + pl * ex2(pm - M);
    m1 = M;
    pm = __shfl_xor(m2, mk, 64); pl = __shfl_xor(l2, mk, 64);
    M = fmaxf(m2, pm);
    l2 = l2 * ex2(m2 - M) + pl * ex2(pm - M);
    m2 = M;
  }
  const float c2 = lamv * l1 / l2;

  // ---------- pass 2: probs + PV, counted-vmcnt pipeline ----------
  f32x4 accv[8];
#pragma unroll
  for (int n = 0; n < 8; ++n) accv[n] = zero4;
  float dln = 0.f;

  STAGE_K(0, t0 * 64);
  STAGE_V(0, t0 * 64);
  asm volatile("s_waitcnt vmcnt(0)" ::: "memory");
  __builtin_amdgcn_s_barrier();
  {
    int cur = 0;
    for (int t = t0; t <= qb; ++t, cur ^= 1) {
      if (t < qb) {
        STAGE_K(cur ^ 1, (t + 1) * 64);
        STAGE_V(cur ^ 1, (t + 1) * 64);
        asm volatile("s_waitcnt vmcnt(8)" ::: "memory");
      } else {
        asm volatile("s_waitcnt vmcnt(0)" ::: "memory");
      }
      __builtin_amdgcn_s_barrier();
      __builtin_amdgcn_sched_barrier(0);
      const int kb0 = t * 64;
      unsigned* pw = (unsigned*)&Pw[w][0];
      f32x4 s1v[4], s2v[4];
      QK_TILE(cur);
      const bool edge = (t == qb) || (qb >= 8 && t == t0);
      if (edge) dln += p2_probs<true>(s1v, s2v, m1, m2, c2, kb0, myq, lhi, l15, pw);
      else      dln += p2_probs<false>(s1v, s2v, m1, m2, c2, kb0, myq, lhi, l15, pw);
#pragma unroll
      for (int kc = 0; kc < 2; ++kc) {
        short8 pa = *(const short8*)(&Pw[w][l15 * 72 + kc * 32 + lhi * 8]);
#pragma unroll
        for (int n = 0; n < 8; ++n)
          accv[n] = MFMA16(pa, VFRAG(cur, n, kc * 4 + lhi), accv[n]);
      }
      __builtin_amdgcn_s_barrier();
    }
  }

  dln += __shfl_xor(dln, 16, 64);
  dln += __shfl_xor(dln, 32, 64);

#pragma unroll
  for (int r = 0; r < 4; ++r) {
    int srcq = lhi * 4 + r;
    int src = (lane & 48) | srcq;
    float dq = __shfl(dln, src, 64);
    float lq = __shfl(l1, src, 64);
    float rinv = 1.f / (dq + lq * 1e-6f);
    int qo = qg + srcq;
#pragma unroll
    for (int n = 0; n < 8; ++n) {
      O[(size_t)qo * 2048 + h * 128 + n * 16 + l15] =
          __float2bfloat16(accv[n][r] * rinv);
    }
  }
#undef STAGE_K
#undef STAGE_V
#undef KFRAG
#undef VFRAG
#undef QK_TILE
}

// ================= launch =================
extern "C" void kernel_launch(void* const* d_in, const int* in_sizes, int n_in,
                              void* d_out, int out_size, void* d_ws, size_t ws_size,
                              hipStream_t stream)
{
  const float* x   = (const float*)d_in[0];
  const float* Wq  = (const float*)d_in[1];
  const float* Wk  = (const float*)d_in[2];
  const float* Wv  = (const float*)d_in[3];
  const float* Wo  = (const float*)d_in[4];
  const float* lam = (const float*)d_in[5];

  char* ws = (char*)d_ws;
  bf16* xb     = (bf16*)(ws);                       // [2048][2048]  8 MB
  bf16* WqkvFT = (bf16*)(ws + 8ull  * (1u << 20));  // FT 3072x2048 12 MB
  bf16* WoFT   = (bf16*)(ws + 20ull * (1u << 20));  // FT 2048x2048  8 MB
  bf16* QKV    = (bf16*)(ws + 28ull * (1u << 20));  // [2048][3072] 12 MB (V region unused)
  bf16* ATT    = (bf16*)(ws + 40ull * (1u << 20));  // [2048][2048]  8 MB
  bf16* VT     = (bf16*)(ws + 48ull * (1u << 20));  // [512][2048]   2 MB

  prep_all<<<dim3(144, 32), 256, 0, stream>>>(x, Wq, Wk, Wv, Wo, xb, WqkvFT, WoFT);
  gemm_ft<0><<<dim3(24, 16), 256, 0, stream>>>(xb, WqkvFT, QKV, VT, 2048, 3072, 2048);
  diff_attn<<<dim3(32, 16), 256, 0, stream>>>(QKV, VT, lam, ATT);
  gemm_ft<1><<<dim3(16, 16), 256, 0, stream>>>(ATT, WoFT, d_out, nullptr, 2048, 2048, 2048);
}

// Round 16
// 106.573 us; speedup vs baseline: 1.1282x; 1.0404x over previous
//
#include <hip/hip_runtime.h>
#include <hip/hip_bf16.h>
#include <stdint.h>

typedef __attribute__((ext_vector_type(8))) short short8;
typedef __attribute__((ext_vector_type(4))) float f32x4;
using bf16 = __hip_bfloat16;

#define MFMA16(a, b, c) __builtin_amdgcn_mfma_f32_16x16x32_bf16((a), (b), (c), 0, 0, 0)

#define GLOAD_LDS16(g, l) __builtin_amdgcn_global_load_lds( \
    (const __attribute__((address_space(1))) void*)(g),     \
    (__attribute__((address_space(3))) void*)(l), 16, 0, 0)

__device__ __forceinline__ unsigned packbf2(float lo, float hi) {
  unsigned r;
  asm("v_cvt_pk_bf16_f32 %0, %1, %2" : "=v"(r) : "v"(lo), "v"(hi));
  return r;
}
__device__ __forceinline__ float ex2(float x) {
  float r;
  asm("v_exp_f32 %0, %1" : "=v"(r) : "v"(x));
  return r;
}
__device__ __forceinline__ f32x4 vmax4(f32x4 a, f32x4 b) {
  f32x4 r;
  r[0] = fmaxf(a[0], b[0]); r[1] = fmaxf(a[1], b[1]);
  r[2] = fmaxf(a[2], b[2]); r[3] = fmaxf(a[3], b[3]);
  return r;
}

template <bool EDGE>
__device__ __forceinline__ void p1_update(const f32x4* sv, float& m, float& l,
                                          int kb0, int myq, int lhi) {
  f32x4 t4 = vmax4(vmax4(sv[0], sv[1]), vmax4(sv[2], sv[3]));
  float tm = fmaxf(fmaxf(t4[0], t4[1]), fmaxf(t4[2], t4[3]));
  float nm = fmaxf(m, tm);
  float sc = ex2(m - nm);
  float sum = 0.f;
#pragma unroll
  for (int nt = 0; nt < 4; ++nt) {
    float part = 0.f;
#pragma unroll
    for (int r = 0; r < 4; ++r) {
      float e = ex2(sv[nt][r] - nm);
      if (EDGE) {
        int key = kb0 + nt * 16 + lhi * 4 + r;
        bool ok = (key <= myq) && (key > myq - 512);
        e = ok ? e : 0.f;
      }
      part += e;
    }
    sum += part;
  }
  l = l * sc + sum;
  m = nm;
}

template <bool EDGE>
__device__ __forceinline__ float p2_probs(const f32x4* s1v, const f32x4* s2v,
                                          float m1, float m2, float c2,
                                          int kb0, int myq, int lhi, int l15,
                                          unsigned* pw) {
  float d0 = 0.f, d1 = 0.f;
#pragma unroll
  for (int nt = 0; nt < 4; ++nt) {
    float pr[4];
#pragma unroll
    for (int r = 0; r < 4; ++r) {
      float e1 = ex2(s1v[nt][r] - m1);
      float e2 = ex2(s2v[nt][r] - m2);
      float p = fmaf(-c2, e2, e1);
      p = fmaxf(p, 0.f);
      if (EDGE) {
        int key = kb0 + nt * 16 + lhi * 4 + r;
        bool ok = (key <= myq) && (key > myq - 512);
        p = ok ? p : 0.f;
      }
      pr[r] = p;
      if (r & 1) d1 += p; else d0 += p;
    }
    int pi = l15 * 36 + 8 * nt + 2 * lhi;
    pw[pi]     = packbf2(pr[0], pr[1]);
    pw[pi + 1] = packbf2(pr[2], pr[3]);
  }
  return d0 + d1;
}

// ================= fused prep: x f32->bf16 row-major + weights -> FT bf16 =================
__global__ __launch_bounds__(256) void prep_all(const float* __restrict__ x,
                                                const float* __restrict__ Wq,
                                                const float* __restrict__ Wk,
                                                const float* __restrict__ Wv,
                                                const float* __restrict__ Wo,
                                                bf16* __restrict__ xb,
                                                bf16* __restrict__ WqkvFT,
                                                bf16* __restrict__ WoFT)
{
  const int bx = blockIdx.x;
  const int tid = threadIdx.x;
  if (bx >= 80) {
    size_t i = ((size_t)(bx - 80) * 32 + blockIdx.y) * 2048 + tid * 8;
    const float* f = x + i;
    float4 a = *(const float4*)f;
    float4 b = *(const float4*)(f + 4);
    union { bf16 h[8]; short8 s; } u;
    u.h[0] = __float2bfloat16(a.x); u.h[1] = __float2bfloat16(a.y);
    u.h[2] = __float2bfloat16(a.z); u.h[3] = __float2bfloat16(a.w);
    u.h[4] = __float2bfloat16(b.x); u.h[5] = __float2bfloat16(b.y);
    u.h[6] = __float2bfloat16(b.z); u.h[7] = __float2bfloat16(b.w);
    *(short8*)(xb + i) = u.s;
    return;
  }
  const float* W;
  bf16* Wt;
  int N, n0;
  if (bx < 32)      { W = Wq; Wt = WqkvFT; N = 2048; n0 = bx * 64; }
  else if (bx < 40) { W = Wk; Wt = WqkvFT; N = 512;  n0 = 2048 + (bx - 32) * 64; }
  else if (bx < 48) { W = Wv; Wt = WqkvFT; N = 512;  n0 = 2560 + (bx - 40) * 64; }
  else              { W = Wo; Wt = WoFT;   N = 2048; n0 = (bx - 48) * 64; }
  const int nloc0 = (N == 512) ? (n0 - ((n0 >= 2560) ? 2560 : 2048)) : ((bx < 32 || bx >= 48) ? (n0 & 2047) : 0);
  const int k0 = blockIdx.y * 64;

  __shared__ bf16 t[64][72];
#pragma unroll
  for (int pass = 0; pass < 4; ++pass) {
    int r = pass * 16 + (tid >> 4);
    int c = (tid & 15) * 4;
    float4 v = *(const float4*)(W + (size_t)(k0 + r) * N + nloc0 + c);
    t[c + 0][r] = __float2bfloat16(v.x);
    t[c + 1][r] = __float2bfloat16(v.y);
    t[c + 2][r] = __float2bfloat16(v.z);
    t[c + 3][r] = __float2bfloat16(v.w);
  }
  __syncthreads();
#pragma unroll
  for (int pass = 0; pass < 2; ++pass) {
    int n = pass * 32 + (tid >> 3);
    int k8 = (tid & 7) * 8;
    int frag = ((n0 + n) >> 4) * 64 + ((k0 + k8) >> 5);
    int ln = (n & 15) + 16 * ((k8 >> 3) & 3);
    *(short8*)(Wt + (size_t)frag * 512 + ln * 8) = *(const short8*)(&t[n][k8]);
  }
}

// ================= QKV GEMM: 128x256 tile, 8 waves (2m x 4n), B frags unique/wave =================
// A LDS-staged (both-sides XOR swizzle), B FT direct-to-VGPR, 4-deep ring (5 loads/stage).
// Fused epilogue: Q/K tiles -> RoPE via 64KB LDS restage; V tiles -> VT direct packed stores.
__global__ __launch_bounds__(512) void gemm_qkv(const bf16* __restrict__ A,
                                                const bf16* __restrict__ Bft,
                                                bf16* __restrict__ QKV,
                                                bf16* __restrict__ VTp,
                                                int M, int N, int K)
{
  __shared__ __align__(16) char smem[65536];
  bf16* As = (bf16*)smem;                     // 4 bufs x 4096 bf16 (32KB)

  const int tid  = threadIdx.x;
  const int lane = tid & 63;
  const int w    = tid >> 6;                  // 0..7
  const int wmg  = (w >> 2) * 4;              // 0 or 4
  const int wng  = (w & 3) * 4;               // 0,4,8,12
  const int l15  = lane & 15;
  const int lhi  = lane >> 4;

  // XCD swizzle: grid (12,16) -> 192 blocks (192 % 8 == 0)
  const int nbx = gridDim.x;                  // 12
  const int lb  = blockIdx.y * nbx + blockIdx.x;
  const int nwg = nbx * gridDim.y;            // 192
  const int lsw = (lb & 7) * (nwg >> 3) + (lb >> 3);
  const int bm0 = (lsw / nbx) * 128;
  const int bn0 = (lsw % nbx) * 256;

  const int srow = tid >> 2;                              // 0..127
  const int scol = ((tid & 3) ^ ((tid >> 3) & 3)) * 8;
  const int loff = l15 * 4 + (lhi ^ ((l15 >> 1) & 3));

  const int nkc = K >> 5;   // 64
  const bf16* bbase[4];
#pragma unroll
  for (int nt = 0; nt < 4; ++nt)
    bbase[nt] = Bft + ((size_t)((bn0 >> 4) + wng + nt) * nkc) * 512 + lane * 8;

  f32x4 acc[4][4];
  const f32x4 zero4 = {0.f, 0.f, 0.f, 0.f};
#pragma unroll
  for (int i = 0; i < 4; ++i)
#pragma unroll
    for (int j = 0; j < 4; ++j) acc[i][j] = zero4;

  short8 br0[4], br1[4], br2[4], br3[4];

#define GSTAGE_A(buf, kk)                                                           \
  { GLOAD_LDS16(A + (size_t)(bm0 + srow) * K + (kk) + scol,                         \
                As + (buf) * 4096 + tid * 8); }

#define BLOAD(breg, kc)                                                             \
  { _Pragma("unroll")                                                               \
    for (int nt = 0; nt < 4; ++nt) {                                                \
      asm volatile("global_load_dwordx4 %0, %1, off"                                \
                   : "=v"(breg[nt])                                                 \
                   : "v"(bbase[nt] + (size_t)(kc) * 512)                            \
                   : "memory");                                                     \
    } }

#define KSTEP(aslot, breg, wcn, ...)                                                \
  {                                                                                 \
    asm volatile("s_waitcnt vmcnt(" #wcn ")" ::: "memory");                         \
    __builtin_amdgcn_s_barrier();                                                   \
    __builtin_amdgcn_sched_barrier(0);                                              \
    __VA_ARGS__                                                                     \
    short8 a_[4];                                                                   \
    _Pragma("unroll")                                                               \
    for (int mt = 0; mt < 4; ++mt)                                                  \
      a_[mt] = *(const short8*)(As + (aslot) * 4096 + ((wmg + mt) * 64 + loff) * 8);\
    _Pragma("unroll")                                                               \
    for (int mt = 0; mt < 4; ++mt)                                                  \
      _Pragma("unroll")                                                             \
      for (int nt = 0; nt < 4; ++nt)                                                \
        acc[mt][nt] = MFMA16(a_[mt], breg[nt], acc[mt][nt]);                        \
  }

  GSTAGE_A(0, 0);  BLOAD(br0, 0);
  GSTAGE_A(1, 32); BLOAD(br1, 1);
  GSTAGE_A(2, 64); BLOAD(br2, 2);

  for (int t = 0; t < nkc - 4; t += 4) {
    KSTEP(0, br0, 10, GSTAGE_A(3, (t + 3) * 32); BLOAD(br3, t + 3);)
    KSTEP(1, br1, 10, GSTAGE_A(0, (t + 4) * 32); BLOAD(br0, t + 4);)
    KSTEP(2, br2, 10, GSTAGE_A(1, (t + 5) * 32); BLOAD(br1, t + 5);)
    KSTEP(3, br3, 10, GSTAGE_A(2, (t + 6) * 32); BLOAD(br2, t + 6);)
  }
  KSTEP(0, br0, 10, GSTAGE_A(3, (nkc - 1) * 32); BLOAD(br3, nkc - 1);)
  KSTEP(1, br1, 10, )
  KSTEP(2, br2, 5, )
  KSTEP(3, br3, 0, )
#undef GSTAGE_A
#undef BLOAD
#undef KSTEP

  __syncthreads();   // ring drained; smem reusable
  if (bn0 < 2560) {
    // ---- Q/K tiles: restage 64x256 f32 half-tile, apply RoPE, write QKV ----
    float* Lf = (float*)smem;   // [64][256] = 64KB
    const float scale = (bn0 < 2048) ? 0.180336880111120f : 1.0f;
#pragma unroll
    for (int half = 0; half < 2; ++half) {
      if ((w >> 2) == half) {
#pragma unroll
        for (int mt = 0; mt < 4; ++mt)
#pragma unroll
          for (int nt = 0; nt < 4; ++nt) {
            int col = (w & 3) * 64 + nt * 16 + l15;
#pragma unroll
            for (int r = 0; r < 4; ++r)
              Lf[(mt * 16 + lhi * 4 + r) * 256 + col] = acc[mt][nt][r];
          }
      }
      __syncthreads();
      {
        int row = tid >> 3;
        int pg = (tid & 7) * 16;        // pair-group base, 16 pairs/thread
        int head = pg >> 6;             // 0 or 1 (run never crosses)
        int din0 = pg & 63;
        int col1 = head * 128 + din0;
        int s = bm0 + half * 64 + row;
        bf16* orow = QKV + (size_t)s * 3072 + bn0;
        union { bf16 h[16]; short8 v[2]; } o1, o2;
#pragma unroll
        for (int e = 0; e < 16; ++e) {
          int din = din0 + e;
          float inv = __expf(-(float)din * (9.210340371976184f / 64.0f));
          float ang = (float)s * inv;
          float cs = __cosf(ang), sn = __sinf(ang);
          float x1 = Lf[row * 256 + col1 + e];
          float x2 = Lf[row * 256 + col1 + e + 64];
          o1.h[e] = __float2bfloat16((x1 * cs - x2 * sn) * scale);
          o2.h[e] = __float2bfloat16((x2 * cs + x1 * sn) * scale);
        }
        *(short8*)(orow + col1)      = o1.v[0];
        *(short8*)(orow + col1 + 8)  = o1.v[1];
        *(short8*)(orow + col1 + 64) = o2.v[0];
        *(short8*)(orow + col1 + 72) = o2.v[1];
      }
      __syncthreads();
    }
  } else {
    // ---- V tiles: write VT directly (acc's 4 rows are consecutive keys -> 8B packed) ----
    const int dimbase = (bn0 - 2560) + (w & 3) * 64;
#pragma unroll
    for (int mt = 0; mt < 4; ++mt) {
#pragma unroll
      for (int nt = 0; nt < 4; ++nt) {
        int dim = dimbase + nt * 16 + l15;
        int key0 = bm0 + (w >> 2) * 64 + mt * 16 + lhi * 4;
        uint2 pk;
        pk.x = packbf2(acc[mt][nt][0], acc[mt][nt][1]);
        pk.y = packbf2(acc[mt][nt][2], acc[mt][nt][3]);
        *(uint2*)(VTp + (size_t)dim * 2048 + key0) = pk;
      }
    }
  }
}

// ================= Wo GEMM: R12-proven hybrid 128x128 (EPI=1 path) =================
__global__ __launch_bounds__(256) void gemm_wo(const bf16* __restrict__ A,
                                               const bf16* __restrict__ Bft,
                                               float* __restrict__ C,
                                               int M, int N, int K)
{
  __shared__ __align__(16) bf16 As[4][128 * 32];

  const int tid  = threadIdx.x;
  const int lane = tid & 63;
  const int w    = tid >> 6;
  const int wmg  = (w >> 1) * 4;
  const int wng  = (w & 1) * 4;
  const int l15  = lane & 15;
  const int lhi  = lane >> 4;

  const int nbx = gridDim.x;
  const int lb  = blockIdx.y * nbx + blockIdx.x;
  const int nwg = nbx * gridDim.y;
  const int lsw = (lb & 7) * (nwg >> 3) + (lb >> 3);
  const int bm0 = (lsw / nbx) * 128;
  const int bn0 = (lsw % nbx) * 128;

  const int srow = lane >> 2;
  const int scol = ((lane & 3) ^ ((lane >> 3) & 3)) * 8;
  const int loff = l15 * 4 + (lhi ^ ((l15 >> 1) & 3));

  const int nkc = K >> 5;
  const bf16* bbase[4];
#pragma unroll
  for (int nt = 0; nt < 4; ++nt)
    bbase[nt] = Bft + ((size_t)((bn0 >> 4) + wng + nt) * nkc) * 512 + lane * 8;

  f32x4 acc[4][4];
  const f32x4 zero4 = {0.f, 0.f, 0.f, 0.f};
#pragma unroll
  for (int i = 0; i < 4; ++i)
#pragma unroll
    for (int j = 0; j < 4; ++j) acc[i][j] = zero4;

  short8 br0[4], br1[4], br2[4], br3[4];

#define GSTAGE_A(buf, kk)                                                          \
  { _Pragma("unroll")                                                              \
    for (int p = 0; p < 2; ++p) {                                                  \
      int s   = (p * 4 + w) * 64 + lane;                                           \
      int row = (p * 4 + w) * 16 + srow;                                           \
      GLOAD_LDS16(A + (size_t)(bm0 + row) * K + (kk) + scol, &As[buf][s * 8]);     \
    } }

#define BLOAD(breg, kc)                                                            \
  { _Pragma("unroll")                                                              \
    for (int nt = 0; nt < 4; ++nt) {                                               \
      asm volatile("global_load_dwordx4 %0, %1, off"                               \
                   : "=v"(breg[nt])                                                \
                   : "v"(bbase[nt] + (size_t)(kc) * 512)                           \
                   : "memory");                                                    \
    } }

#define KSTEP(aslot, breg, wcn, ...)                                               \
  {                                                                                \
    asm volatile("s_waitcnt vmcnt(" #wcn ")" ::: "memory");                        \
    __builtin_amdgcn_s_barrier();                                                  \
    __builtin_amdgcn_sched_barrier(0);                                             \
    __VA_ARGS__                                                                    \
    short8 a_[4];                                                                  \
    _Pragma("unroll")                                                              \
    for (int mt = 0; mt < 4; ++mt)                                                 \
      a_[mt] = *(const short8*)(&As[aslot][((wmg + mt) * 64 + loff) * 8]);         \
    _Pragma("unroll")                                                              \
    for (int mt = 0; mt < 4; ++mt)                                                 \
      _Pragma("unroll")                                                            \
      for (int nt = 0; nt < 4; ++nt)                                               \
        acc[mt][nt] = MFMA16(a_[mt], breg[nt], acc[mt][nt]);                       \
  }

  GSTAGE_A(0, 0);  BLOAD(br0, 0);
  GSTAGE_A(1, 32); BLOAD(br1, 1);
  GSTAGE_A(2, 64); BLOAD(br2, 2);

  for (int t = 0; t < nkc - 4; t += 4) {
    KSTEP(0, br0, 12, GSTAGE_A(3, (t + 3) * 32); BLOAD(br3, t + 3);)
    KSTEP(1, br1, 12, GSTAGE_A(0, (t + 4) * 32); BLOAD(br0, t + 4);)
    KSTEP(2, br2, 12, GSTAGE_A(1, (t + 5) * 32); BLOAD(br1, t + 5);)
    KSTEP(3, br3, 12, GSTAGE_A(2, (t + 6) * 32); BLOAD(br2, t + 6);)
  }
  KSTEP(0, br0, 12, GSTAGE_A(3, (nkc - 1) * 32); BLOAD(br3, nkc - 1);)
  KSTEP(1, br1, 12, )
  KSTEP(2, br2, 6, )
  KSTEP(3, br3, 0, )
#undef GSTAGE_A
#undef BLOAD
#undef KSTEP

#pragma unroll
  for (int mt = 0; mt < 4; ++mt) {
    int row0 = bm0 + (wmg + mt) * 16 + lhi * 4;
#pragma unroll
    for (int nt = 0; nt < 4; ++nt) {
      int col = bn0 + (wng + nt) * 16 + l15;
#pragma unroll
      for (int r = 0; r < 4; ++r)
        C[(size_t)(row0 + r) * N + col] = acc[mt][nt][r];
    }
  }
}

// ================= Differential sliding-window attention (swapped-QK, log2 domain) =================
__global__ __launch_bounds__(256) void diff_attn(const bf16* __restrict__ QKV,
                                                 const bf16* __restrict__ VT,
                                                 const float* __restrict__ lam,
                                                 bf16* __restrict__ O)
{
  __shared__ __align__(16) bf16 Kb[2][64 * 128];
  __shared__ __align__(16) bf16 Vb[2][128 * 64];
  __shared__ __align__(16) bf16 Pw[4][16 * 72];

  const int lb  = blockIdx.y * 32 + blockIdx.x;
  const int lsw = (lb & 7) * 64 + (lb >> 3);
  const int qb  = lsw & 31;
  const int h   = lsw >> 5;

  const int kvh  = h >> 2;
  const int tid  = threadIdx.x;
  const int lane = tid & 63;
  const int w    = tid >> 6;
  const int l15  = lane & 15;
  const int lhi  = lane >> 4;
  const int qg   = qb * 64 + w * 16;
  const int myq  = qg + l15;
  const float lamv = lam[h];

  const bf16* Kg = QKV + 2048 + (size_t)kvh * 128;
  const bf16* Vg = VT + (size_t)kvh * 128 * 2048;

  short8 qf[4];
  {
    const bf16* qrow = QKV + (size_t)myq * 3072 + h * 128;
#pragma unroll
    for (int c = 0; c < 4; ++c)
      qf[c] = *(const short8*)(qrow + c * 32 + lhi * 8);
  }

  const int t0 = (qb >= 8) ? (qb - 8) : 0;

#define STAGE_K(buf, kbase)                                                     \
  {                                                                             \
    _Pragma("unroll")                                                           \
    for (int p = 0; p < 4; ++p) {                                               \
      int c = p * 256 + tid;                                                    \
      int r = c >> 4, q = c & 15;                                               \
      GLOAD_LDS16(Kg + (size_t)((kbase) + r) * 3072 + ((q ^ (r & 7)) * 8),      \
                  &Kb[buf][c * 8]);                                             \
    }                                                                           \
  }
#define STAGE_V(buf, kbase)                                                     \
  {                                                                             \
    _Pragma("unroll")                                                           \
    for (int p = 0; p < 4; ++p) {                                               \
      int c = p * 256 + tid;                                                    \
      int d = c >> 3, q = c & 7;                                                \
      GLOAD_LDS16(Vg + (size_t)d * 2048 + (kbase) + ((q ^ (d & 7)) * 8),        \
                  &Vb[buf][c * 8]);                                             \
    }                                                                           \
  }
#define KFRAG(buf, nt, qc) \
  (*(const short8*)(&Kb[buf][(((nt) * 16 + l15) * 16 + ((qc) ^ (((nt) * 16 + l15) & 7))) * 8]))
#define VFRAG(buf, n, qc) \
  (*(const short8*)(&Vb[buf][(((n) * 16 + l15) * 8 + ((qc) ^ (((n) * 16 + l15) & 7))) * 8]))
#define QK_TILE(cur)                                            \
  _Pragma("unroll")                                             \
  for (int nt = 0; nt < 4; ++nt) {                              \
    f32x4 s1 = zero4, s2 = zero4;                               \
    s1 = MFMA16(KFRAG(cur, nt, lhi),      qf[0], s1);           \
    s1 = MFMA16(KFRAG(cur, nt, 4 + lhi),  qf[1], s1);           \
    s2 = MFMA16(KFRAG(cur, nt, 8 + lhi),  qf[2], s2);           \
    s2 = MFMA16(KFRAG(cur, nt, 12 + lhi), qf[3], s2);           \
    s1v[nt] = s1; s2v[nt] = s2;                                 \
  }

  const f32x4 zero4 = {0.f, 0.f, 0.f, 0.f};

  float m1 = -1e30f, l1 = 0.f, m2 = -1e30f, l2 = 0.f;
  STAGE_K(0, t0 * 64);
  asm volatile("s_waitcnt vmcnt(0)" ::: "memory");
  __builtin_amdgcn_s_barrier();
  {
    int cur = 0;
    for (int t = t0; t <= qb; ++t, cur ^= 1) {
      if (t < qb) {
        STAGE_K(cur ^ 1, (t + 1) * 64);
        asm volatile("s_waitcnt vmcnt(4)" ::: "memory");
      } else {
        asm volatile("s_waitcnt vmcnt(0)" ::: "memory");
      }
      __builtin_amdgcn_s_barrier();
      __builtin_amdgcn_sched_barrier(0);
      const int kb0 = t * 64;
      f32x4 s1v[4], s2v[4];
      QK_TILE(cur);
      const bool edge = (t == qb) || (qb >= 8 && t == t0);
      if (edge) {
        p1_update<true>(s1v, m1, l1, kb0, myq, lhi);
        p1_update<true>(s2v, m2, l2, kb0, myq, lhi);
      } else {
        p1_update<false>(s1v, m1, l1, kb0, myq, lhi);
        p1_update<false>(s2v, m2, l2, kb0, myq, lhi);
      }
      __builtin_amdgcn_s_barrier();
    }
  }

#pragma unroll
  for (int mk = 16; mk <= 32; mk <<= 1) {
    float pm = __shfl_xor(m1, mk, 64), pl = __shfl_xor(l1, mk, 64);
    float M = fmaxf(m1, pm);
    l1 = l1 * ex2(m1 - M) + pl * ex2(pm - M);
    m1 = M;
    pm = __shfl_xor(m2, mk, 64); pl = __shfl_xor(l2, mk, 64);
    M = fmaxf(m2, pm);
    l2 = l2 * ex2(m2 - M) + pl * ex2(pm - M);
    m2 = M;
  }
  const float c2 = lamv * l1 / l2;

  f32x4 accv[8];
#pragma unroll
  for (int n = 0; n < 8; ++n) accv[n] = zero4;
  float dln = 0.f;

  STAGE_K(0, t0 * 64);
  STAGE_V(0, t0 * 64);
  asm volatile("s_waitcnt vmcnt(0)" ::: "memory");
  __builtin_amdgcn_s_barrier();
  {
    int cur = 0;
    for (int t = t0; t <= qb; ++t, cur ^= 1) {
      if (t < qb) {
        STAGE_K(cur ^ 1, (t + 1) * 64);
        STAGE_V(cur ^ 1, (t + 1) * 64);
        asm volatile("s_waitcnt vmcnt(8)" ::: "memory");
      } else {
        asm volatile("s_waitcnt vmcnt(0)" ::: "memory");
      }
      __builtin_amdgcn_s_barrier();
      __builtin_amdgcn_sched_barrier(0);
      const int kb0 = t * 64;
      unsigned* pw = (unsigned*)&Pw[w][0];
      f32x4 s1v[4], s2v[4];
      QK_TILE(cur);
      const bool edge = (t == qb) || (qb >= 8 && t == t0);
      if (edge) dln += p2_probs<true>(s1v, s2v, m1, m2, c2, kb0, myq, lhi, l15, pw);
      else      dln += p2_probs<false>(s1v, s2v, m1, m2, c2, kb0, myq, lhi, l15, pw);
#pragma unroll
      for (int kc = 0; kc < 2; ++kc) {
        short8 pa = *(const short8*)(&Pw[w][l15 * 72 + kc * 32 + lhi * 8]);
#pragma unroll
        for (int n = 0; n < 8; ++n)
          accv[n] = MFMA16(pa, VFRAG(cur, n, kc * 4 + lhi), accv[n]);
      }
      __builtin_amdgcn_s_barrier();
    }
  }

  dln += __shfl_xor(dln, 16, 64);
  dln += __shfl_xor(dln, 32, 64);

#pragma unroll
  for (int r = 0; r < 4; ++r) {
    int srcq = lhi * 4 + r;
    int src = (lane & 48) | srcq;
    float dq = __shfl(dln, src, 64);
    float lq = __shfl(l1, src, 64);
    float rinv = 1.f / (dq + lq * 1e-6f);
    int qo = qg + srcq;
#pragma unroll
    for (int n = 0; n < 8; ++n) {
      O[(size_t)qo * 2048 + h * 128 + n * 16 + l15] =
          __float2bfloat16(accv[n][r] * rinv);
    }
  }
#undef STAGE_K
#undef STAGE_V
#undef KFRAG
#undef VFRAG
#undef QK_TILE
}

// ================= launch =================
extern "C" void kernel_launch(void* const* d_in, const int* in_sizes, int n_in,
                              void* d_out, int out_size, void* d_ws, size_t ws_size,
                              hipStream_t stream)
{
  const float* x   = (const float*)d_in[0];
  const float* Wq  = (const float*)d_in[1];
  const float* Wk  = (const float*)d_in[2];
  const float* Wv  = (const float*)d_in[3];
  const float* Wo  = (const float*)d_in[4];
  const float* lam = (const float*)d_in[5];

  char* ws = (char*)d_ws;
  bf16* xb     = (bf16*)(ws);                       // [2048][2048]  8 MB
  bf16* WqkvFT = (bf16*)(ws + 8ull  * (1u << 20));  // FT 3072x2048 12 MB
  bf16* WoFT   = (bf16*)(ws + 20ull * (1u << 20));  // FT 2048x2048  8 MB
  bf16* QKV    = (bf16*)(ws + 28ull * (1u << 20));  // [2048][3072] 12 MB (V region unused)
  bf16* ATT    = (bf16*)(ws + 40ull * (1u << 20));  // [2048][2048]  8 MB
  bf16* VT     = (bf16*)(ws + 48ull * (1u << 20));  // [512][2048]   2 MB

  prep_all<<<dim3(144, 32), 256, 0, stream>>>(x, Wq, Wk, Wv, Wo, xb, WqkvFT, WoFT);
  gemm_qkv<<<dim3(12, 16), 512, 0, stream>>>(xb, WqkvFT, QKV, VT, 2048, 3072, 2048);
  diff_attn<<<dim3(32, 16), 256, 0, stream>>>(QKV, VT, lam, ATT);
  gemm_wo<<<dim3(16, 16), 256, 0, stream>>>(ATT, WoFT, (float*)d_out, 2048, 2048, 2048);
}